// Round 1
// baseline (1175.062 us; speedup 1.0000x reference)
//
#include <hip/hip_runtime.h>
#include <hip/hip_bf16.h>
#include <math.h>
#include <stdint.h>

#define T_ 2048
#define NTOK 4096

typedef unsigned short bf16_t;
typedef __attribute__((ext_vector_type(8))) short short8;
typedef __attribute__((ext_vector_type(4))) float f32x4;
typedef __attribute__((ext_vector_type(4))) unsigned short us4;

__device__ __forceinline__ bf16_t f2bf(float f) {
  unsigned u = __float_as_uint(f);
  u += 0x7fffu + ((u >> 16) & 1u);
  return (bf16_t)(u >> 16);
}
__device__ __forceinline__ float bf2f(bf16_t h) {
  return __uint_as_float(((unsigned)h) << 16);
}
__device__ __forceinline__ float sigm(float x) { return 1.f / (1.f + __expf(-x)); }

__device__ __forceinline__ void gload_lds16(const bf16_t* g, bf16_t* l) {
  __builtin_amdgcn_global_load_lds(
      (const __attribute__((address_space(1))) void*)g,
      (__attribute__((address_space(3))) void*)l, 16, 0, 0);
}

// ---------------------------------------------------------------------------
// Generic bf16 MFMA GEMM: C[M,N] = A[M,K] * BT[N,K]^T (+ fused epilogues)
// 128x128 tile, BK=32, 256 threads = 4 waves, each wave 64x64 as 4x4 MFMA.
// MODE 0: outf = acc + bias
// MODE 5: outb = bf16(acc + bias)
// MODE 1: outb = bf16((acc+bias + d0[col]*xb0) * sigmoid(xb1))   (z epilogue)
// MODE 2: v = acc+bias+xf0 -> outf and outf2                     (x2 + accum init)
// MODE 3: outb = bf16(gelu_exact(acc+bias))                      (expert hidden)
// MODE 4: if (scale4[row*4]) outf += scale4[row*4]*(acc+bias)    (expert out)
// ---------------------------------------------------------------------------
template <int MODE>
__global__ __launch_bounds__(256) void gemm_bt(
    const bf16_t* __restrict__ A, const bf16_t* __restrict__ BT,
    int M, int N, int K,
    float* __restrict__ outf, bf16_t* __restrict__ outb,
    const float* __restrict__ bias,
    const bf16_t* __restrict__ xb0, int xs0,
    const bf16_t* __restrict__ xb1, int xs1,
    const float* __restrict__ xf0, int xfs0,
    const float* __restrict__ d0,
    const float* __restrict__ scale4,
    float* __restrict__ outf2) {
  __shared__ __align__(16) bf16_t As[128 * 32];
  __shared__ __align__(16) bf16_t Bs[128 * 32];
  const int tid = threadIdx.x;
  const int wave = tid >> 6;
  const int lane = tid & 63;
  const long m0 = (long)blockIdx.y * 128;
  const long n0 = (long)blockIdx.x * 128;

  f32x4 acc[4][4];
#pragma unroll
  for (int i = 0; i < 4; ++i)
#pragma unroll
    for (int j = 0; j < 4; ++j) acc[i][j] = f32x4{0.f, 0.f, 0.f, 0.f};

  const int rowL = tid >> 2;          // 0..63
  const int kseg = (tid & 3) * 8;     // 0,8,16,24
  const bf16_t* gA = A + (m0 + rowL) * K + kseg;
  const bf16_t* gB = BT + (n0 + rowL) * K + kseg;
  bf16_t* lA = As + wave * 512;       // wave-uniform LDS base (+lane*16B by HW)
  bf16_t* lB = Bs + wave * 512;

  const int wm = (wave & 1) * 64;
  const int wn = (wave >> 1) * 64;
  const int lm = lane & 15;
  const int kq = (lane >> 4) * 8;

  for (int k0 = 0; k0 < K; k0 += 32) {
    gload_lds16(gA + k0, lA);
    gload_lds16(gA + (long)64 * K + k0, lA + 2048);
    gload_lds16(gB + k0, lB);
    gload_lds16(gB + (long)64 * K + k0, lB + 2048);
    __syncthreads();
    short8 af[4], bfr[4];
#pragma unroll
    for (int i = 0; i < 4; ++i)
      af[i] = *(const short8*)(As + (wm + i * 16 + lm) * 32 + kq);
#pragma unroll
    for (int j = 0; j < 4; ++j)
      bfr[j] = *(const short8*)(Bs + (wn + j * 16 + lm) * 32 + kq);
#pragma unroll
    for (int i = 0; i < 4; ++i)
#pragma unroll
      for (int j = 0; j < 4; ++j)
        acc[i][j] = __builtin_amdgcn_mfma_f32_16x16x32_bf16(af[i], bfr[j], acc[i][j], 0, 0, 0);
    __syncthreads();
  }

  const int er = (lane >> 4) * 4;  // C/D: row=(lane>>4)*4+reg, col=lane&15
  const int ec = lane & 15;
#pragma unroll
  for (int i = 0; i < 4; ++i) {
#pragma unroll
    for (int j = 0; j < 4; ++j) {
#pragma unroll
      for (int r = 0; r < 4; ++r) {
        long row = m0 + wm + i * 16 + er + r;
        long col = n0 + wn + j * 16 + ec;
        float v = acc[i][j][r] + bias[col];
        if constexpr (MODE == 0) {
          outf[row * N + col] = v;
        } else if constexpr (MODE == 5) {
          outb[row * N + col] = f2bf(v);
        } else if constexpr (MODE == 1) {
          float xm = bf2f(xb0[row * (long)xs0 + col]);
          float g = bf2f(xb1[row * (long)xs1 + col]);
          v = (v + d0[col] * xm) * sigm(g);
          outb[row * N + col] = f2bf(v);
        } else if constexpr (MODE == 2) {
          v += xf0[row * (long)xfs0 + col];
          outf[row * N + col] = v;
          outf2[row * N + col] = v;
        } else if constexpr (MODE == 3) {
          v = 0.5f * v * (1.f + erff(v * 0.70710678118654752f));
          outb[row * N + col] = f2bf(v);
        } else if constexpr (MODE == 4) {
          float s = scale4[row * 4];
          if (s != 0.f) outf[row * N + col] += s * v;
        }
      }
    }
  }
}

// fp32 [R,C] -> bf16 [C,R]  (weights to B^T layout)
__global__ __launch_bounds__(256) void tcast_k(const float* __restrict__ in,
                                               bf16_t* __restrict__ out, int R, int C) {
  __shared__ float tile[32][33];
  const int tx = threadIdx.x, ty = threadIdx.y;
  const long c0 = (long)blockIdx.x * 32, r0 = (long)blockIdx.y * 32;
#pragma unroll
  for (int i = 0; i < 4; ++i) {
    int r = ty + i * 8;
    tile[r][tx] = in[(r0 + r) * (long)C + c0 + tx];
  }
  __syncthreads();
#pragma unroll
  for (int i = 0; i < 4; ++i) {
    int r = ty + i * 8;
    out[(c0 + r) * (long)R + r0 + tx] = f2bf(tile[tx][r]);
  }
}

__global__ void dtbias_k(const float* __restrict__ dtb, const float* __restrict__ bpb,
                         const float* __restrict__ cpb, float* __restrict__ out) {
  int i = threadIdx.x;
  float v = 0.f;
  if (i < 64) v = dtb[i];
  else if (i < 128) v = bpb[i - 64];
  else if (i < 192) v = cpb[i - 128];
  out[i] = v;
}

// rmsnorm over D=1024, one block per row; bf16 out (+ optional fp32 out)
__global__ __launch_bounds__(256) void rmsnorm_k(const float* __restrict__ x,
                                                 const float* __restrict__ w,
                                                 bf16_t* __restrict__ ob,
                                                 float* __restrict__ of, int has_f) {
  const long row = blockIdx.x;
  const int tid = threadIdx.x;
  const int wave = tid >> 6, lane = tid & 63;
  const float4 v = ((const float4*)(x + row * 1024))[tid];
  float ss = v.x * v.x + v.y * v.y + v.z * v.z + v.w * v.w;
#pragma unroll
  for (int off = 32; off > 0; off >>= 1) ss += __shfl_down(ss, off);
  __shared__ float sred[4];
  if (lane == 0) sred[wave] = ss;
  __syncthreads();
  float tot = sred[0] + sred[1] + sred[2] + sred[3];
  float nr = rsqrtf(tot * (1.f / 1024.f) + 1e-6f);
  const float4 wv = ((const float4*)w)[tid];
  float o0 = v.x * nr * wv.x, o1 = v.y * nr * wv.y;
  float o2 = v.z * nr * wv.z, o3 = v.w * nr * wv.w;
  us4 o;
  o.x = f2bf(o0); o.y = f2bf(o1); o.z = f2bf(o2); o.w = f2bf(o3);
  ((us4*)ob)[row * 256 + tid] = o;
  if (has_f) ((float4*)of)[row * 256 + tid] = make_float4(o0, o1, o2, o3);
}

// causal depthwise conv (K=3) + bias + silu, bf16 in/out
__global__ __launch_bounds__(256) void conv_silu_k(const bf16_t* __restrict__ xz,
                                                   const float* __restrict__ cw,
                                                   const float* __restrict__ cb,
                                                   bf16_t* __restrict__ xs) {
  long idx = (long)blockIdx.x * 256 + threadIdx.x;  // < 4096*2048
  int c = (int)(idx & 2047);
  long row = idx >> 11;
  int t = (int)(row & 2047);
  const bf16_t* p = xz + row * 4096 + c;
  float v = bf2f(p[0]) * cw[c * 3 + 2];
  if (t >= 1) v += bf2f(*(p - 4096)) * cw[c * 3 + 1];
  if (t >= 2) v += bf2f(*(p - 8192)) * cw[c * 3 + 0];
  v += cb[c];
  v = v * sigm(v);
  xs[idx] = f2bf(v);
}

// parallel linear-recurrence scan: one block per (b, s) channel
// state = (1-dt)*state + dt*B ; y = C*state. dtBC rows [tok][256]: dt|B|C|pad
__global__ __launch_bounds__(256) void scan_k(const float* __restrict__ dtbc,
                                              float* __restrict__ y) {
  const int bid = blockIdx.x;  // 0..127
  const int b = bid >> 6, s = bid & 63;
  const int tid = threadIdx.x;
  const float* base = dtbc + (long)b * T_ * 256;
  const int t0 = tid * 8;
  float A = 1.f, U = 0.f;
#pragma unroll
  for (int i = 0; i < 8; ++i) {
    const float* r = base + (long)(t0 + i) * 256;
    float dt = sigm(r[s]);
    float bv = r[64 + s];
    U = (1.f - dt) * U + dt * bv;
    A = (1.f - dt) * A;
  }
  __shared__ float sA[256], sU[256];
  sA[tid] = A; sU[tid] = U;
  __syncthreads();
  for (int off = 1; off < 256; off <<= 1) {
    float pA = 1.f, pU = 0.f;
    if (tid >= off) { pA = sA[tid - off]; pU = sU[tid - off]; }
    __syncthreads();
    U = A * pU + U;
    A = A * pA;
    sA[tid] = A; sU[tid] = U;
    __syncthreads();
  }
  float st = (tid == 0) ? 0.f : sU[tid - 1];
#pragma unroll
  for (int i = 0; i < 8; ++i) {
    const float* r = base + (long)(t0 + i) * 256;
    float dt = sigm(r[s]);
    float bv = r[64 + s];
    st = (1.f - dt) * st + dt * bv;
    y[((long)b * T_ + t0 + i) * 64 + s] = r[128 + s] * st;
  }
}

// layernorm over S=64, one wave per row
__global__ __launch_bounds__(256) void ln64_k(const float* __restrict__ y,
                                              bf16_t* __restrict__ yb) {
  const int tid = threadIdx.x;
  const int wave = tid >> 6, lane = tid & 63;
  const long row = (long)blockIdx.x * 4 + wave;
  float v = y[row * 64 + lane];
  float m = v;
#pragma unroll
  for (int off = 32; off > 0; off >>= 1) m += __shfl_xor(m, off);
  m *= (1.f / 64.f);
  float d = v - m;
  float var = d * d;
#pragma unroll
  for (int off = 32; off > 0; off >>= 1) var += __shfl_xor(var, off);
  var *= (1.f / 64.f);
  yb[row * 64 + lane] = f2bf(d * rsqrtf(var + 1e-5f));
}

// router: logits (fp32), top-2 softmax -> per-expert combine weights [tok][4]
__global__ __launch_bounds__(256) void gate_k(const float* __restrict__ h2,
                                              const float* __restrict__ gw,
                                              const float* __restrict__ gb,
                                              float* __restrict__ w4) {
  const int tid = threadIdx.x;
  const int wave = tid >> 6, lane = tid & 63;
  const long t = (long)blockIdx.x * 4 + wave;
  float a0 = 0, a1 = 0, a2 = 0, a3 = 0;
#pragma unroll
  for (int i = 0; i < 16; ++i) {
    int d = lane + i * 64;
    float h = h2[t * 1024 + d];
    float4 w = ((const float4*)gw)[d];
    a0 += h * w.x; a1 += h * w.y; a2 += h * w.z; a3 += h * w.w;
  }
#pragma unroll
  for (int off = 32; off > 0; off >>= 1) {
    a0 += __shfl_xor(a0, off); a1 += __shfl_xor(a1, off);
    a2 += __shfl_xor(a2, off); a3 += __shfl_xor(a3, off);
  }
  if (lane == 0) {
    float lg[4] = {a0 + gb[0], a1 + gb[1], a2 + gb[2], a3 + gb[3]};
    int i0 = 0;
    for (int e = 1; e < 4; ++e)
      if (lg[e] > lg[i0]) i0 = e;
    int i1 = -1;
    for (int e = 0; e < 4; ++e) {
      if (e == i0) continue;
      if (i1 < 0 || lg[e] > lg[i1]) i1 = e;
    }
    float e1 = __expf(lg[i1] - lg[i0]);
    float p0 = 1.f / (1.f + e1), p1 = e1 / (1.f + e1);
    float o[4] = {0.f, 0.f, 0.f, 0.f};
    o[i0] = p0; o[i1] = p1;
    w4[t * 4 + 0] = o[0]; w4[t * 4 + 1] = o[1];
    w4[t * 4 + 2] = o[2]; w4[t * 4 + 3] = o[3];
  }
}

extern "C" void kernel_launch(void* const* d_in, const int* in_sizes, int n_in,
                              void* d_out, int out_size, void* d_ws, size_t ws_size,
                              hipStream_t stream) {
  const float* x = (const float*)d_in[0];
  const float* n1w = (const float*)d_in[1];
  const float* n2w = (const float*)d_in[2];
  const float* inpw = (const float*)d_in[3];
  const float* inpb = (const float*)d_in[4];
  const float* convw = (const float*)d_in[5];
  const float* convb = (const float*)d_in[6];
  const float* dtw = (const float*)d_in[7];
  const float* dtb = (const float*)d_in[8];
  const float* bpw = (const float*)d_in[9];
  const float* bpb = (const float*)d_in[10];
  const float* cpw = (const float*)d_in[11];
  const float* cpb = (const float*)d_in[12];
  const float* s2iw = (const float*)d_in[13];
  const float* s2ib = (const float*)d_in[14];
  const float* Dp = (const float*)d_in[15];
  const float* outw = (const float*)d_in[16];
  const float* outb_ = (const float*)d_in[17];
  const float* gatew = (const float*)d_in[18];
  const float* gateb = (const float*)d_in[19];
  const float* ew1 = (const float*)d_in[20];
  const float* eb1 = (const float*)d_in[21];
  const float* ew2 = (const float*)d_in[22];
  const float* eb2 = (const float*)d_in[23];
  float* out = (float*)d_out;

  char* ws = (char*)d_ws;
  size_t off = 0;
  auto alloc = [&](size_t bytes) -> void* {
    void* p = (void*)(ws + off);
    off += (bytes + 255) & ~(size_t)255;
    return p;
  };

  bf16_t* h1b = (bf16_t*)alloc((size_t)NTOK * 1024 * 2);
  bf16_t* inpT = (bf16_t*)alloc((size_t)4096 * 1024 * 2);
  bf16_t* wdtT = (bf16_t*)alloc((size_t)256 * 2048 * 2);
  float* biasdt = (float*)alloc(256 * 4);
  float* ybuf = (float*)alloc((size_t)NTOK * 64 * 4);
  bf16_t* ylnb = (bf16_t*)alloc((size_t)NTOK * 64 * 2);
  bf16_t* s2iT = (bf16_t*)alloc((size_t)2048 * 64 * 2);
  bf16_t* outT = (bf16_t*)alloc((size_t)1024 * 2048 * 2);
  float* x2 = (float*)alloc((size_t)NTOK * 1024 * 4);
  bf16_t* h2b = (bf16_t*)alloc((size_t)NTOK * 1024 * 2);
  float* h2f = (float*)alloc((size_t)NTOK * 1024 * 4);
  float* w4 = (float*)alloc((size_t)NTOK * 4 * 4);
  // union region: mixer temporaries, later reused by MoE temporaries
  const size_t SZ_XZ = (size_t)NTOK * 4096 * 2;   // 32MB
  const size_t SZ_XS = (size_t)NTOK * 2048 * 2;   // 16MB
  const size_t SZ_DT = (size_t)NTOK * 256 * 4;    // 4MB
  const size_t SZ_Z = (size_t)NTOK * 2048 * 2;    // 16MB
  char* reg = (char*)alloc(SZ_XZ + SZ_XS + SZ_DT + SZ_Z);
  bf16_t* xzb = (bf16_t*)reg;
  bf16_t* xsb = (bf16_t*)(reg + SZ_XZ);
  float* dtbc = (float*)(reg + SZ_XZ + SZ_XS);
  bf16_t* zb = (bf16_t*)(reg + SZ_XZ + SZ_XS + SZ_DT);
  bf16_t* ew1T = (bf16_t*)reg;                       // 8MB (aliases dead xzb)
  bf16_t* ew2T = (bf16_t*)(reg + 8388608);           // 8MB
  bf16_t* hidb = (bf16_t*)(reg + 16777216);          // 32MB

  dim3 tb(32, 8);
  hipMemsetAsync(wdtT, 0, (size_t)256 * 2048 * 2, stream);
  dtbias_k<<<1, 256, 0, stream>>>(dtb, bpb, cpb, biasdt);
  tcast_k<<<dim3(128, 32), tb, 0, stream>>>(inpw, inpT, 1024, 4096);
  tcast_k<<<dim3(2, 64), tb, 0, stream>>>(dtw, wdtT, 2048, 64);
  tcast_k<<<dim3(2, 64), tb, 0, stream>>>(bpw, wdtT + (size_t)64 * 2048, 2048, 64);
  tcast_k<<<dim3(2, 64), tb, 0, stream>>>(cpw, wdtT + (size_t)128 * 2048, 2048, 64);
  tcast_k<<<dim3(64, 2), tb, 0, stream>>>(s2iw, s2iT, 64, 2048);
  tcast_k<<<dim3(32, 64), tb, 0, stream>>>(outw, outT, 2048, 1024);

  // ---- mixer ----
  rmsnorm_k<<<NTOK, 256, 0, stream>>>(x, n1w, h1b, nullptr, 0);
  gemm_bt<5><<<dim3(32, 32), 256, 0, stream>>>(h1b, inpT, NTOK, 4096, 1024,
      nullptr, xzb, inpb, nullptr, 0, nullptr, 0, nullptr, 0, nullptr, nullptr, nullptr);
  conv_silu_k<<<(NTOK * 2048) / 256, 256, 0, stream>>>(xzb, convw, convb, xsb);
  gemm_bt<0><<<dim3(2, 32), 256, 0, stream>>>(xsb, wdtT, NTOK, 256, 2048,
      dtbc, nullptr, biasdt, nullptr, 0, nullptr, 0, nullptr, 0, nullptr, nullptr, nullptr);
  scan_k<<<128, 256, 0, stream>>>(dtbc, ybuf);
  ln64_k<<<NTOK / 4, 256, 0, stream>>>(ybuf, ylnb);
  gemm_bt<1><<<dim3(16, 32), 256, 0, stream>>>(ylnb, s2iT, NTOK, 2048, 64,
      nullptr, zb, s2ib, xsb, 2048, xzb + 2048, 4096, nullptr, 0, Dp, nullptr, nullptr);
  gemm_bt<2><<<dim3(8, 32), 256, 0, stream>>>(zb, outT, NTOK, 1024, 2048,
      x2, nullptr, outb_, nullptr, 0, nullptr, 0, x, 1024, nullptr, nullptr, out);

  // ---- MoE ----
  rmsnorm_k<<<NTOK, 256, 0, stream>>>(x2, n2w, h2b, h2f, 1);
  gate_k<<<NTOK / 4, 256, 0, stream>>>(h2f, gatew, gateb, w4);
  for (int e = 0; e < 4; ++e) {
    tcast_k<<<dim3(128, 32), tb, 0, stream>>>(ew1 + (size_t)e * 1024 * 4096, ew1T, 1024, 4096);
    gemm_bt<3><<<dim3(32, 32), 256, 0, stream>>>(h2b, ew1T, NTOK, 4096, 1024,
        nullptr, hidb, eb1 + (size_t)e * 4096, nullptr, 0, nullptr, 0, nullptr, 0,
        nullptr, nullptr, nullptr);
    tcast_k<<<dim3(32, 128), tb, 0, stream>>>(ew2 + (size_t)e * 4096 * 1024, ew2T, 4096, 1024);
    gemm_bt<4><<<dim3(8, 32), 256, 0, stream>>>(hidb, ew2T, NTOK, 1024, 4096,
        out, nullptr, eb2 + (size_t)e * 1024, nullptr, 0, nullptr, 0, nullptr, 0,
        nullptr, w4 + e, nullptr);
  }
}

// Round 2
// 1121.892 us; speedup vs baseline: 1.0474x; 1.0474x over previous
//
#include <hip/hip_runtime.h>
#include <hip/hip_bf16.h>
#include <math.h>
#include <stdint.h>

#define T_ 2048
#define NTOK 4096

typedef unsigned short bf16_t;
typedef __attribute__((ext_vector_type(8))) short short8;
typedef __attribute__((ext_vector_type(4))) float f32x4;
typedef __attribute__((ext_vector_type(4))) unsigned short us4;

__device__ __forceinline__ bf16_t f2bf(float f) {
  unsigned u = __float_as_uint(f);
  u += 0x7fffu + ((u >> 16) & 1u);
  return (bf16_t)(u >> 16);
}
__device__ __forceinline__ float bf2f(bf16_t h) {
  return __uint_as_float(((unsigned)h) << 16);
}
__device__ __forceinline__ float sigm(float x) { return 1.f / (1.f + __expf(-x)); }

__device__ __forceinline__ void gload_lds16(const bf16_t* g, bf16_t* l) {
  __builtin_amdgcn_global_load_lds(
      (const __attribute__((address_space(1))) void*)g,
      (__attribute__((address_space(3))) void*)l, 16, 0, 0);
}

// ---------------------------------------------------------------------------
// Generic bf16 MFMA GEMM: C[M,N] = A[M,K] * BT[N,K]^T (+ fused epilogues)
// 128x128 tile, K-step 64 as two BK=32 sub-buffers (keeps 64B LDS row stride),
// XCD-aware tile swizzle: id%8 -> XCD, per-XCD 2D patch (8 m-tiles x tn/2
// n-tiles, m fastest) so each XCD's L2 working set <= ~4MB.
// Requires gridDim.y % 4 == 0, gridDim.x % 2 == 0, K % 64 == 0.
// MODE 0: outf = acc + bias
// MODE 5: outb = bf16(acc + bias)
// MODE 1: outb = bf16((acc+bias + d0[col]*xb0) * sigmoid(xb1))   (z epilogue)
// MODE 2: v = acc+bias+xf0 -> outf and outf2                     (x2 + accum init)
// MODE 3: outb = bf16(gelu_exact(acc+bias))                      (expert hidden)
// MODE 4: if (scale4[row*4]) outf += scale4[row*4]*(acc+bias)    (expert out)
// ---------------------------------------------------------------------------
template <int MODE>
__global__ __launch_bounds__(256) void gemm_bt(
    const bf16_t* __restrict__ A, const bf16_t* __restrict__ BT,
    int M, int N, int K,
    float* __restrict__ outf, bf16_t* __restrict__ outb,
    const float* __restrict__ bias,
    const bf16_t* __restrict__ xb0, int xs0,
    const bf16_t* __restrict__ xb1, int xs1,
    const float* __restrict__ xf0, int xfs0,
    const float* __restrict__ d0,
    const float* __restrict__ scale4,
    float* __restrict__ outf2) {
  __shared__ __align__(16) bf16_t As[2][128 * 32];
  __shared__ __align__(16) bf16_t Bs[2][128 * 32];
  const int tid = threadIdx.x;
  const int wave = tid >> 6;
  const int lane = tid & 63;

  // XCD-aware swizzle
  const int tn = gridDim.x, tm = gridDim.y;
  const int id = blockIdx.y * tn + blockIdx.x;
  const int xcd = id & 7;
  const int s = id >> 3;
  const int pm = tm >> 2;          // m-tiles per XCD patch (8 for tm=32)
  const int pn = tn >> 1;          // n-tiles per XCD patch
  const int mt = (xcd & 3) * pm + (s % pm);
  const int nt = (xcd >> 2) * pn + (s / pm);
  const long m0 = (long)mt * 128;
  const long n0 = (long)nt * 128;

  f32x4 acc[4][4];
#pragma unroll
  for (int i = 0; i < 4; ++i)
#pragma unroll
    for (int j = 0; j < 4; ++j) acc[i][j] = f32x4{0.f, 0.f, 0.f, 0.f};

  const int rowL = tid >> 2;          // 0..63
  const int kseg = (tid & 3) * 8;     // 0,8,16,24
  const bf16_t* gA = A + (m0 + rowL) * K + kseg;
  const bf16_t* gB = BT + (n0 + rowL) * K + kseg;
  bf16_t* lA0 = As[0] + wave * 512;   // wave-uniform LDS base (+lane*16B by HW)
  bf16_t* lB0 = Bs[0] + wave * 512;
  bf16_t* lA1 = As[1] + wave * 512;
  bf16_t* lB1 = Bs[1] + wave * 512;

  const int wm = (wave & 1) * 64;
  const int wn = (wave >> 1) * 64;
  const int lm = lane & 15;
  const int kq = (lane >> 4) * 8;

  for (int k0 = 0; k0 < K; k0 += 64) {
    gload_lds16(gA + k0, lA0);
    gload_lds16(gA + (long)64 * K + k0, lA0 + 2048);
    gload_lds16(gB + k0, lB0);
    gload_lds16(gB + (long)64 * K + k0, lB0 + 2048);
    gload_lds16(gA + k0 + 32, lA1);
    gload_lds16(gA + (long)64 * K + k0 + 32, lA1 + 2048);
    gload_lds16(gB + k0 + 32, lB1);
    gload_lds16(gB + (long)64 * K + k0 + 32, lB1 + 2048);
    __syncthreads();
#pragma unroll
    for (int h = 0; h < 2; ++h) {
      short8 af[4], bfr[4];
#pragma unroll
      for (int i = 0; i < 4; ++i)
        af[i] = *(const short8*)(As[h] + (wm + i * 16 + lm) * 32 + kq);
#pragma unroll
      for (int j = 0; j < 4; ++j)
        bfr[j] = *(const short8*)(Bs[h] + (wn + j * 16 + lm) * 32 + kq);
#pragma unroll
      for (int i = 0; i < 4; ++i)
#pragma unroll
        for (int j = 0; j < 4; ++j)
          acc[i][j] = __builtin_amdgcn_mfma_f32_16x16x32_bf16(af[i], bfr[j], acc[i][j], 0, 0, 0);
    }
    __syncthreads();
  }

  const int er = (lane >> 4) * 4;  // C/D: row=(lane>>4)*4+reg, col=lane&15
  const int ec = lane & 15;
#pragma unroll
  for (int i = 0; i < 4; ++i) {
#pragma unroll
    for (int j = 0; j < 4; ++j) {
#pragma unroll
      for (int r = 0; r < 4; ++r) {
        long row = m0 + wm + i * 16 + er + r;
        long col = n0 + wn + j * 16 + ec;
        float v = acc[i][j][r] + bias[col];
        if constexpr (MODE == 0) {
          outf[row * N + col] = v;
        } else if constexpr (MODE == 5) {
          outb[row * N + col] = f2bf(v);
        } else if constexpr (MODE == 1) {
          float xm = bf2f(xb0[row * (long)xs0 + col]);
          float g = bf2f(xb1[row * (long)xs1 + col]);
          v = (v + d0[col] * xm) * sigm(g);
          outb[row * N + col] = f2bf(v);
        } else if constexpr (MODE == 2) {
          v += xf0[row * (long)xfs0 + col];
          outf[row * N + col] = v;
          outf2[row * N + col] = v;
        } else if constexpr (MODE == 3) {
          v = 0.5f * v * (1.f + erff(v * 0.70710678118654752f));
          outb[row * N + col] = f2bf(v);
        } else if constexpr (MODE == 4) {
          float s4 = scale4[row * 4];
          if (s4 != 0.f) outf[row * N + col] += s4 * v;
        }
      }
    }
  }
}

// fp32 [R,C] -> bf16 [C,R]  (weights to B^T layout)
__global__ __launch_bounds__(256) void tcast_k(const float* __restrict__ in,
                                               bf16_t* __restrict__ out, int R, int C) {
  __shared__ float tile[32][33];
  const int tx = threadIdx.x, ty = threadIdx.y;
  const long c0 = (long)blockIdx.x * 32, r0 = (long)blockIdx.y * 32;
#pragma unroll
  for (int i = 0; i < 4; ++i) {
    int r = ty + i * 8;
    tile[r][tx] = in[(r0 + r) * (long)C + c0 + tx];
  }
  __syncthreads();
#pragma unroll
  for (int i = 0; i < 4; ++i) {
    int r = ty + i * 8;
    out[(c0 + r) * (long)R + r0 + tx] = f2bf(tile[tx][r]);
  }
}

__global__ void dtbias_k(const float* __restrict__ dtb, const float* __restrict__ bpb,
                         const float* __restrict__ cpb, float* __restrict__ out) {
  int i = threadIdx.x;
  float v = 0.f;
  if (i < 64) v = dtb[i];
  else if (i < 128) v = bpb[i - 64];
  else if (i < 192) v = cpb[i - 128];
  out[i] = v;
}

// rmsnorm over D=1024, one block per row; bf16 out (+ optional fp32 out)
__global__ __launch_bounds__(256) void rmsnorm_k(const float* __restrict__ x,
                                                 const float* __restrict__ w,
                                                 bf16_t* __restrict__ ob,
                                                 float* __restrict__ of, int has_f) {
  const long row = blockIdx.x;
  const int tid = threadIdx.x;
  const int wave = tid >> 6, lane = tid & 63;
  const float4 v = ((const float4*)(x + row * 1024))[tid];
  float ss = v.x * v.x + v.y * v.y + v.z * v.z + v.w * v.w;
#pragma unroll
  for (int off = 32; off > 0; off >>= 1) ss += __shfl_down(ss, off);
  __shared__ float sred[4];
  if (lane == 0) sred[wave] = ss;
  __syncthreads();
  float tot = sred[0] + sred[1] + sred[2] + sred[3];
  float nr = rsqrtf(tot * (1.f / 1024.f) + 1e-6f);
  const float4 wv = ((const float4*)w)[tid];
  float o0 = v.x * nr * wv.x, o1 = v.y * nr * wv.y;
  float o2 = v.z * nr * wv.z, o3 = v.w * nr * wv.w;
  us4 o;
  o.x = f2bf(o0); o.y = f2bf(o1); o.z = f2bf(o2); o.w = f2bf(o3);
  ((us4*)ob)[row * 256 + tid] = o;
  if (has_f) ((float4*)of)[row * 256 + tid] = make_float4(o0, o1, o2, o3);
}

// causal depthwise conv (K=3) + bias + silu, bf16 in/out
__global__ __launch_bounds__(256) void conv_silu_k(const bf16_t* __restrict__ xz,
                                                   const float* __restrict__ cw,
                                                   const float* __restrict__ cb,
                                                   bf16_t* __restrict__ xs) {
  long idx = (long)blockIdx.x * 256 + threadIdx.x;  // < 4096*2048
  int c = (int)(idx & 2047);
  long row = idx >> 11;
  int t = (int)(row & 2047);
  const bf16_t* p = xz + row * 4096 + c;
  float v = bf2f(p[0]) * cw[c * 3 + 2];
  if (t >= 1) v += bf2f(*(p - 4096)) * cw[c * 3 + 1];
  if (t >= 2) v += bf2f(*(p - 8192)) * cw[c * 3 + 0];
  v += cb[c];
  v = v * sigm(v);
  xs[idx] = f2bf(v);
}

// parallel linear-recurrence scan: one block per (b, s) channel
// state = (1-dt)*state + dt*B ; y = C*state. dtBC rows [tok][256]: dt|B|C|pad
__global__ __launch_bounds__(256) void scan_k(const float* __restrict__ dtbc,
                                              float* __restrict__ y) {
  const int bid = blockIdx.x;  // 0..127
  const int b = bid >> 6, s = bid & 63;
  const int tid = threadIdx.x;
  const float* base = dtbc + (long)b * T_ * 256;
  const int t0 = tid * 8;
  float A = 1.f, U = 0.f;
#pragma unroll
  for (int i = 0; i < 8; ++i) {
    const float* r = base + (long)(t0 + i) * 256;
    float dt = sigm(r[s]);
    float bv = r[64 + s];
    U = (1.f - dt) * U + dt * bv;
    A = (1.f - dt) * A;
  }
  __shared__ float sA[256], sU[256];
  sA[tid] = A; sU[tid] = U;
  __syncthreads();
  for (int off = 1; off < 256; off <<= 1) {
    float pA = 1.f, pU = 0.f;
    if (tid >= off) { pA = sA[tid - off]; pU = sU[tid - off]; }
    __syncthreads();
    U = A * pU + U;
    A = A * pA;
    sA[tid] = A; sU[tid] = U;
    __syncthreads();
  }
  float st = (tid == 0) ? 0.f : sU[tid - 1];
#pragma unroll
  for (int i = 0; i < 8; ++i) {
    const float* r = base + (long)(t0 + i) * 256;
    float dt = sigm(r[s]);
    float bv = r[64 + s];
    st = (1.f - dt) * st + dt * bv;
    y[((long)b * T_ + t0 + i) * 64 + s] = r[128 + s] * st;
  }
}

// layernorm over S=64, one wave per row
__global__ __launch_bounds__(256) void ln64_k(const float* __restrict__ y,
                                              bf16_t* __restrict__ yb) {
  const int tid = threadIdx.x;
  const int wave = tid >> 6, lane = tid & 63;
  const long row = (long)blockIdx.x * 4 + wave;
  float v = y[row * 64 + lane];
  float m = v;
#pragma unroll
  for (int off = 32; off > 0; off >>= 1) m += __shfl_xor(m, off);
  m *= (1.f / 64.f);
  float d = v - m;
  float var = d * d;
#pragma unroll
  for (int off = 32; off > 0; off >>= 1) var += __shfl_xor(var, off);
  var *= (1.f / 64.f);
  yb[row * 64 + lane] = f2bf(d * rsqrtf(var + 1e-5f));
}

// router: logits (fp32), top-2 softmax -> per-expert combine weights [tok][4]
__global__ __launch_bounds__(256) void gate_k(const float* __restrict__ h2,
                                              const float* __restrict__ gw,
                                              const float* __restrict__ gb,
                                              float* __restrict__ w4) {
  const int tid = threadIdx.x;
  const int wave = tid >> 6, lane = tid & 63;
  const long t = (long)blockIdx.x * 4 + wave;
  float a0 = 0, a1 = 0, a2 = 0, a3 = 0;
#pragma unroll
  for (int i = 0; i < 16; ++i) {
    int d = lane + i * 64;
    float h = h2[t * 1024 + d];
    float4 w = ((const float4*)gw)[d];
    a0 += h * w.x; a1 += h * w.y; a2 += h * w.z; a3 += h * w.w;
  }
#pragma unroll
  for (int off = 32; off > 0; off >>= 1) {
    a0 += __shfl_xor(a0, off); a1 += __shfl_xor(a1, off);
    a2 += __shfl_xor(a2, off); a3 += __shfl_xor(a3, off);
  }
  if (lane == 0) {
    float lg[4] = {a0 + gb[0], a1 + gb[1], a2 + gb[2], a3 + gb[3]};
    int i0 = 0;
    for (int e = 1; e < 4; ++e)
      if (lg[e] > lg[i0]) i0 = e;
    int i1 = -1;
    for (int e = 0; e < 4; ++e) {
      if (e == i0) continue;
      if (i1 < 0 || lg[e] > lg[i1]) i1 = e;
    }
    float e1 = __expf(lg[i1] - lg[i0]);
    float p0 = 1.f / (1.f + e1), p1 = e1 / (1.f + e1);
    float o[4] = {0.f, 0.f, 0.f, 0.f};
    o[i0] = p0; o[i1] = p1;
    w4[t * 4 + 0] = o[0]; w4[t * 4 + 1] = o[1];
    w4[t * 4 + 2] = o[2]; w4[t * 4 + 3] = o[3];
  }
}

extern "C" void kernel_launch(void* const* d_in, const int* in_sizes, int n_in,
                              void* d_out, int out_size, void* d_ws, size_t ws_size,
                              hipStream_t stream) {
  const float* x = (const float*)d_in[0];
  const float* n1w = (const float*)d_in[1];
  const float* n2w = (const float*)d_in[2];
  const float* inpw = (const float*)d_in[3];
  const float* inpb = (const float*)d_in[4];
  const float* convw = (const float*)d_in[5];
  const float* convb = (const float*)d_in[6];
  const float* dtw = (const float*)d_in[7];
  const float* dtb = (const float*)d_in[8];
  const float* bpw = (const float*)d_in[9];
  const float* bpb = (const float*)d_in[10];
  const float* cpw = (const float*)d_in[11];
  const float* cpb = (const float*)d_in[12];
  const float* s2iw = (const float*)d_in[13];
  const float* s2ib = (const float*)d_in[14];
  const float* Dp = (const float*)d_in[15];
  const float* outw = (const float*)d_in[16];
  const float* outb_ = (const float*)d_in[17];
  const float* gatew = (const float*)d_in[18];
  const float* gateb = (const float*)d_in[19];
  const float* ew1 = (const float*)d_in[20];
  const float* eb1 = (const float*)d_in[21];
  const float* ew2 = (const float*)d_in[22];
  const float* eb2 = (const float*)d_in[23];
  float* out = (float*)d_out;

  char* ws = (char*)d_ws;
  size_t off = 0;
  auto alloc = [&](size_t bytes) -> void* {
    void* p = (void*)(ws + off);
    off += (bytes + 255) & ~(size_t)255;
    return p;
  };

  bf16_t* h1b = (bf16_t*)alloc((size_t)NTOK * 1024 * 2);
  bf16_t* inpT = (bf16_t*)alloc((size_t)4096 * 1024 * 2);
  bf16_t* wdtT = (bf16_t*)alloc((size_t)256 * 2048 * 2);
  float* biasdt = (float*)alloc(256 * 4);
  float* ybuf = (float*)alloc((size_t)NTOK * 64 * 4);
  bf16_t* ylnb = (bf16_t*)alloc((size_t)NTOK * 64 * 2);
  bf16_t* s2iT = (bf16_t*)alloc((size_t)2048 * 64 * 2);
  bf16_t* outT = (bf16_t*)alloc((size_t)1024 * 2048 * 2);
  float* x2 = (float*)alloc((size_t)NTOK * 1024 * 4);
  bf16_t* h2b = (bf16_t*)alloc((size_t)NTOK * 1024 * 2);
  float* h2f = (float*)alloc((size_t)NTOK * 1024 * 4);
  float* w4 = (float*)alloc((size_t)NTOK * 4 * 4);
  // union region: mixer temporaries, later reused by MoE temporaries
  const size_t SZ_XZ = (size_t)NTOK * 4096 * 2;   // 32MB
  const size_t SZ_XS = (size_t)NTOK * 2048 * 2;   // 16MB
  const size_t SZ_DT = (size_t)NTOK * 256 * 4;    // 4MB
  const size_t SZ_Z = (size_t)NTOK * 2048 * 2;    // 16MB
  char* reg = (char*)alloc(SZ_XZ + SZ_XS + SZ_DT + SZ_Z);
  bf16_t* xzb = (bf16_t*)reg;
  bf16_t* xsb = (bf16_t*)(reg + SZ_XZ);
  float* dtbc = (float*)(reg + SZ_XZ + SZ_XS);
  bf16_t* zb = (bf16_t*)(reg + SZ_XZ + SZ_XS + SZ_DT);
  bf16_t* ew1T = (bf16_t*)reg;                       // 8MB (aliases dead xzb)
  bf16_t* ew2T = (bf16_t*)(reg + 8388608);           // 8MB
  bf16_t* hidb = (bf16_t*)(reg + 16777216);          // 32MB

  dim3 tb(32, 8);
  hipMemsetAsync(wdtT, 0, (size_t)256 * 2048 * 2, stream);
  dtbias_k<<<1, 256, 0, stream>>>(dtb, bpb, cpb, biasdt);
  tcast_k<<<dim3(128, 32), tb, 0, stream>>>(inpw, inpT, 1024, 4096);
  tcast_k<<<dim3(2, 64), tb, 0, stream>>>(dtw, wdtT, 2048, 64);
  tcast_k<<<dim3(2, 64), tb, 0, stream>>>(bpw, wdtT + (size_t)64 * 2048, 2048, 64);
  tcast_k<<<dim3(2, 64), tb, 0, stream>>>(cpw, wdtT + (size_t)128 * 2048, 2048, 64);
  tcast_k<<<dim3(64, 2), tb, 0, stream>>>(s2iw, s2iT, 64, 2048);
  tcast_k<<<dim3(32, 64), tb, 0, stream>>>(outw, outT, 2048, 1024);

  // ---- mixer ----
  rmsnorm_k<<<NTOK, 256, 0, stream>>>(x, n1w, h1b, nullptr, 0);
  gemm_bt<5><<<dim3(32, 32), 256, 0, stream>>>(h1b, inpT, NTOK, 4096, 1024,
      nullptr, xzb, inpb, nullptr, 0, nullptr, 0, nullptr, 0, nullptr, nullptr, nullptr);
  conv_silu_k<<<(NTOK * 2048) / 256, 256, 0, stream>>>(xzb, convw, convb, xsb);
  gemm_bt<0><<<dim3(2, 32), 256, 0, stream>>>(xsb, wdtT, NTOK, 256, 2048,
      dtbc, nullptr, biasdt, nullptr, 0, nullptr, 0, nullptr, 0, nullptr, nullptr, nullptr);
  scan_k<<<128, 256, 0, stream>>>(dtbc, ybuf);
  ln64_k<<<NTOK / 4, 256, 0, stream>>>(ybuf, ylnb);
  gemm_bt<1><<<dim3(16, 32), 256, 0, stream>>>(ylnb, s2iT, NTOK, 2048, 64,
      nullptr, zb, s2ib, xsb, 2048, xzb + 2048, 4096, nullptr, 0, Dp, nullptr, nullptr);
  gemm_bt<2><<<dim3(8, 32), 256, 0, stream>>>(zb, outT, NTOK, 1024, 2048,
      x2, nullptr, outb_, nullptr, 0, nullptr, 0, x, 1024, nullptr, nullptr, out);

  // ---- MoE ----
  rmsnorm_k<<<NTOK, 256, 0, stream>>>(x2, n2w, h2b, h2f, 1);
  gate_k<<<NTOK / 4, 256, 0, stream>>>(h2f, gatew, gateb, w4);
  for (int e = 0; e < 4; ++e) {
    tcast_k<<<dim3(128, 32), tb, 0, stream>>>(ew1 + (size_t)e * 1024 * 4096, ew1T, 1024, 4096);
    gemm_bt<3><<<dim3(32, 32), 256, 0, stream>>>(h2b, ew1T, NTOK, 4096, 1024,
        nullptr, hidb, eb1 + (size_t)e * 4096, nullptr, 0, nullptr, 0, nullptr, 0,
        nullptr, nullptr, nullptr);
    tcast_k<<<dim3(32, 128), tb, 0, stream>>>(ew2 + (size_t)e * 4096 * 1024, ew2T, 4096, 1024);
    gemm_bt<4><<<dim3(8, 32), 256, 0, stream>>>(hidb, ew2T, NTOK, 1024, 4096,
        out, nullptr, eb2 + (size_t)e * 1024, nullptr, 0, nullptr, 0, nullptr, 0,
        nullptr, w4 + e, nullptr);
  }
}

// Round 3
// 1040.173 us; speedup vs baseline: 1.1297x; 1.0786x over previous
//
#include <hip/hip_runtime.h>
#include <hip/hip_bf16.h>
#include <math.h>
#include <stdint.h>

#define T_ 2048
#define NTOK 4096

typedef unsigned short bf16_t;
typedef __attribute__((ext_vector_type(8))) short short8;
typedef __attribute__((ext_vector_type(4))) float f32x4;
typedef __attribute__((ext_vector_type(4))) unsigned short us4;

__device__ __forceinline__ bf16_t f2bf(float f) {
  unsigned u = __float_as_uint(f);
  u += 0x7fffu + ((u >> 16) & 1u);
  return (bf16_t)(u >> 16);
}
__device__ __forceinline__ float bf2f(bf16_t h) {
  return __uint_as_float(((unsigned)h) << 16);
}
__device__ __forceinline__ float sigm(float x) { return 1.f / (1.f + __expf(-x)); }

__device__ __forceinline__ void gload_lds16(const bf16_t* g, bf16_t* l) {
  __builtin_amdgcn_global_load_lds(
      (const __attribute__((address_space(1))) void*)g,
      (__attribute__((address_space(3))) void*)l, 16, 0, 0);
}

// ---------------------------------------------------------------------------
// bf16 MFMA GEMM: C[M,N] = A[M,K] * BT[N,K]^T, 128xBN tile (BN=128 or 64),
// K-step 64 as two BK=32 sub-buffers. XOR bank swizzle on k-chunks kills the
// 4-cyc/read LDS conflict (row stride 64B -> lane groups hit 2/8 bank quads).
// XCD patch swizzle for L2 locality. Optional sparse row gather (MODE 3) /
// scatter-accum (MODE 6) with early exit on *cntp.
// MODE 0: outf = acc + bias
// MODE 5: outb = bf16(acc + bias)
// MODE 1: outb = bf16((acc+bias + d0[col]*xb0) * sigmoid(xb1))
// MODE 2: v = acc+bias+xf0 -> outf and outf2
// MODE 3: sparse gather-A via gidx; outb = bf16(gelu(acc+bias)) rows<cnt
// MODE 6: sparse: t=gidx[row]; outf[t*N+col] += scale4[t*4]*(acc+bias)
// ---------------------------------------------------------------------------
template <int MODE, int BN>
__global__ __launch_bounds__(256) void gemm_bt(
    const bf16_t* __restrict__ A, const bf16_t* __restrict__ BT,
    int M, int N, int K,
    float* __restrict__ outf, bf16_t* __restrict__ outb,
    const float* __restrict__ bias,
    const bf16_t* __restrict__ xb0, int xs0,
    const bf16_t* __restrict__ xb1, int xs1,
    const float* __restrict__ xf0, int xfs0,
    const float* __restrict__ d0,
    const float* __restrict__ scale4,
    float* __restrict__ outf2,
    const int* __restrict__ gidx,
    const int* __restrict__ cntp) {
  constexpr int NJ = BN / 32;  // n-tiles per wave (4 or 2)
  __shared__ __align__(16) bf16_t As[2][128 * 32];
  __shared__ __align__(16) bf16_t Bs[2][BN * 32];
  const int tid = threadIdx.x;
  const int wave = tid >> 6;
  const int lane = tid & 63;

  // XCD-aware patch swizzle (id%8 -> XCD assumed)
  const int tn = gridDim.x, tm = gridDim.y;
  const int id = blockIdx.y * tn + blockIdx.x;
  const int xcd = id & 7;
  const int s = id >> 3;
  const int pm = tm >> 2;
  const int pn = tn >> 1;
  const int mt = (xcd & 3) * pm + (s % pm);
  const int nt = (xcd >> 2) * pn + (s / pm);
  const long m0 = (long)mt * 128;
  const long n0 = (long)nt * BN;

  int cnt = M;
  if (cntp) {
    cnt = *cntp;
    if (m0 >= cnt) return;
  }

  f32x4 acc[4][NJ];
#pragma unroll
  for (int i = 0; i < 4; ++i)
#pragma unroll
    for (int j = 0; j < NJ; ++j) acc[i][j] = f32x4{0.f, 0.f, 0.f, 0.f};

  const int rowL = tid >> 2;  // 0..63
  const int qL = tid & 3;
  const int ks = (qL ^ ((rowL >> 1) & 3)) * 8;  // XOR-swizzled k-chunk
  long r0 = m0 + rowL, r1 = m0 + rowL + 64;
  if constexpr (MODE == 3) {
    r0 = gidx[(r0 < cnt) ? r0 : 0];
    r1 = gidx[(r1 < cnt) ? r1 : 0];
  }
  const bf16_t* pA0 = A + r0 * (long)K + ks;
  const bf16_t* pA1 = A + r1 * (long)K + ks;
  const bf16_t* pB0 = BT + (n0 + rowL) * (long)K + ks;
  const bf16_t* pB1 = BT + (n0 + rowL + 64) * (long)K + ks;  // BN=128 only
  bf16_t* lA0 = As[0] + wave * 512;
  bf16_t* lB0 = Bs[0] + wave * 512;
  bf16_t* lA1 = As[1] + wave * 512;
  bf16_t* lB1 = Bs[1] + wave * 512;

  const int wm = (wave & 1) * 64;
  const int wn = (wave >> 1) * (BN / 2);
  const int lm = lane & 15;
  const int kq = ((lane >> 4) ^ ((lm >> 1) & 3)) * 8;  // swizzled read offset

  for (int k0 = 0; k0 < K; k0 += 64) {
    gload_lds16(pA0 + k0, lA0);
    gload_lds16(pA1 + k0, lA0 + 2048);
    gload_lds16(pB0 + k0, lB0);
    if constexpr (BN == 128) gload_lds16(pB1 + k0, lB0 + 2048);
    gload_lds16(pA0 + k0 + 32, lA1);
    gload_lds16(pA1 + k0 + 32, lA1 + 2048);
    gload_lds16(pB0 + k0 + 32, lB1);
    if constexpr (BN == 128) gload_lds16(pB1 + k0 + 32, lB1 + 2048);
    __syncthreads();
#pragma unroll
    for (int h = 0; h < 2; ++h) {
      short8 af[4], bfr[NJ];
#pragma unroll
      for (int i = 0; i < 4; ++i)
        af[i] = *(const short8*)(As[h] + (wm + i * 16 + lm) * 32 + kq);
#pragma unroll
      for (int j = 0; j < NJ; ++j)
        bfr[j] = *(const short8*)(Bs[h] + (wn + j * 16 + lm) * 32 + kq);
#pragma unroll
      for (int i = 0; i < 4; ++i)
#pragma unroll
        for (int j = 0; j < NJ; ++j)
          acc[i][j] = __builtin_amdgcn_mfma_f32_16x16x32_bf16(af[i], bfr[j], acc[i][j], 0, 0, 0);
    }
    __syncthreads();
  }

  const int er = (lane >> 4) * 4;  // C/D: row=(lane>>4)*4+reg, col=lane&15
  const int ec = lane & 15;
#pragma unroll
  for (int i = 0; i < 4; ++i) {
#pragma unroll
    for (int j = 0; j < NJ; ++j) {
#pragma unroll
      for (int r = 0; r < 4; ++r) {
        long row = m0 + wm + i * 16 + er + r;
        long col = n0 + wn + j * 16 + ec;
        float v = acc[i][j][r] + bias[col];
        if constexpr (MODE == 0) {
          outf[row * N + col] = v;
        } else if constexpr (MODE == 5) {
          outb[row * N + col] = f2bf(v);
        } else if constexpr (MODE == 1) {
          float xm = bf2f(xb0[row * (long)xs0 + col]);
          float g = bf2f(xb1[row * (long)xs1 + col]);
          v = (v + d0[col] * xm) * sigm(g);
          outb[row * N + col] = f2bf(v);
        } else if constexpr (MODE == 2) {
          v += xf0[row * (long)xfs0 + col];
          outf[row * N + col] = v;
          outf2[row * N + col] = v;
        } else if constexpr (MODE == 3) {
          if (row < cnt) {
            v = 0.5f * v * (1.f + erff(v * 0.70710678118654752f));
            outb[row * N + col] = f2bf(v);
          }
        } else if constexpr (MODE == 6) {
          if (row < cnt) {
            long t = gidx[row];
            outf[t * N + col] += scale4[t * 4] * v;
          }
        }
      }
    }
  }
}

// fp32 [R,C] -> bf16 [C,R]  (weights to B^T layout)
__global__ __launch_bounds__(256) void tcast_k(const float* __restrict__ in,
                                               bf16_t* __restrict__ out, int R, int C) {
  __shared__ float tile[32][33];
  const int tx = threadIdx.x, ty = threadIdx.y;
  const long c0 = (long)blockIdx.x * 32, r0 = (long)blockIdx.y * 32;
#pragma unroll
  for (int i = 0; i < 4; ++i) {
    int r = ty + i * 8;
    tile[r][tx] = in[(r0 + r) * (long)C + c0 + tx];
  }
  __syncthreads();
#pragma unroll
  for (int i = 0; i < 4; ++i) {
    int r = ty + i * 8;
    out[(c0 + r) * (long)R + r0 + tx] = f2bf(tile[tx][r]);
  }
}

__global__ void dtbias_k(const float* __restrict__ dtb, const float* __restrict__ bpb,
                         const float* __restrict__ cpb, float* __restrict__ out) {
  int i = threadIdx.x;
  float v = 0.f;
  if (i < 64) v = dtb[i];
  else if (i < 128) v = bpb[i - 64];
  else if (i < 192) v = cpb[i - 128];
  out[i] = v;
}

// rmsnorm over D=1024, one block per row; bf16 out (+ optional fp32 out)
__global__ __launch_bounds__(256) void rmsnorm_k(const float* __restrict__ x,
                                                 const float* __restrict__ w,
                                                 bf16_t* __restrict__ ob,
                                                 float* __restrict__ of, int has_f) {
  const long row = blockIdx.x;
  const int tid = threadIdx.x;
  const int wave = tid >> 6, lane = tid & 63;
  const float4 v = ((const float4*)(x + row * 1024))[tid];
  float ss = v.x * v.x + v.y * v.y + v.z * v.z + v.w * v.w;
#pragma unroll
  for (int off = 32; off > 0; off >>= 1) ss += __shfl_down(ss, off);
  __shared__ float sred[4];
  if (lane == 0) sred[wave] = ss;
  __syncthreads();
  float tot = sred[0] + sred[1] + sred[2] + sred[3];
  float nr = rsqrtf(tot * (1.f / 1024.f) + 1e-6f);
  const float4 wv = ((const float4*)w)[tid];
  float o0 = v.x * nr * wv.x, o1 = v.y * nr * wv.y;
  float o2 = v.z * nr * wv.z, o3 = v.w * nr * wv.w;
  us4 o;
  o.x = f2bf(o0); o.y = f2bf(o1); o.z = f2bf(o2); o.w = f2bf(o3);
  ((us4*)ob)[row * 256 + tid] = o;
  if (has_f) ((float4*)of)[row * 256 + tid] = make_float4(o0, o1, o2, o3);
}

// causal depthwise conv (K=3) + bias + silu, bf16 in/out
__global__ __launch_bounds__(256) void conv_silu_k(const bf16_t* __restrict__ xz,
                                                   const float* __restrict__ cw,
                                                   const float* __restrict__ cb,
                                                   bf16_t* __restrict__ xs) {
  long idx = (long)blockIdx.x * 256 + threadIdx.x;  // < 4096*2048
  int c = (int)(idx & 2047);
  long row = idx >> 11;
  int t = (int)(row & 2047);
  const bf16_t* p = xz + row * 4096 + c;
  float v = bf2f(p[0]) * cw[c * 3 + 2];
  if (t >= 1) v += bf2f(*(p - 4096)) * cw[c * 3 + 1];
  if (t >= 2) v += bf2f(*(p - 8192)) * cw[c * 3 + 0];
  v += cb[c];
  v = v * sigm(v);
  xs[idx] = f2bf(v);
}

// parallel linear-recurrence scan: one block per (b, s) channel
__global__ __launch_bounds__(256) void scan_k(const float* __restrict__ dtbc,
                                              float* __restrict__ y) {
  const int bid = blockIdx.x;  // 0..127
  const int b = bid >> 6, s = bid & 63;
  const int tid = threadIdx.x;
  const float* base = dtbc + (long)b * T_ * 256;
  const int t0 = tid * 8;
  float A = 1.f, U = 0.f;
#pragma unroll
  for (int i = 0; i < 8; ++i) {
    const float* r = base + (long)(t0 + i) * 256;
    float dt = sigm(r[s]);
    float bv = r[64 + s];
    U = (1.f - dt) * U + dt * bv;
    A = (1.f - dt) * A;
  }
  __shared__ float sA[256], sU[256];
  sA[tid] = A; sU[tid] = U;
  __syncthreads();
  for (int off = 1; off < 256; off <<= 1) {
    float pA = 1.f, pU = 0.f;
    if (tid >= off) { pA = sA[tid - off]; pU = sU[tid - off]; }
    __syncthreads();
    U = A * pU + U;
    A = A * pA;
    sA[tid] = A; sU[tid] = U;
    __syncthreads();
  }
  float st = (tid == 0) ? 0.f : sU[tid - 1];
#pragma unroll
  for (int i = 0; i < 8; ++i) {
    const float* r = base + (long)(t0 + i) * 256;
    float dt = sigm(r[s]);
    float bv = r[64 + s];
    st = (1.f - dt) * st + dt * bv;
    y[((long)b * T_ + t0 + i) * 64 + s] = r[128 + s] * st;
  }
}

// layernorm over S=64, one wave per row
__global__ __launch_bounds__(256) void ln64_k(const float* __restrict__ y,
                                              bf16_t* __restrict__ yb) {
  const int tid = threadIdx.x;
  const int wave = tid >> 6, lane = tid & 63;
  const long row = (long)blockIdx.x * 4 + wave;
  float v = y[row * 64 + lane];
  float m = v;
#pragma unroll
  for (int off = 32; off > 0; off >>= 1) m += __shfl_xor(m, off);
  m *= (1.f / 64.f);
  float d = v - m;
  float var = d * d;
#pragma unroll
  for (int off = 32; off > 0; off >>= 1) var += __shfl_xor(var, off);
  var *= (1.f / 64.f);
  yb[row * 64 + lane] = f2bf(d * rsqrtf(var + 1e-5f));
}

// router: top-2 softmax -> per-expert combine weights [tok][4]
__global__ __launch_bounds__(256) void gate_k(const float* __restrict__ h2,
                                              const float* __restrict__ gw,
                                              const float* __restrict__ gb,
                                              float* __restrict__ w4) {
  const int tid = threadIdx.x;
  const int wave = tid >> 6, lane = tid & 63;
  const long t = (long)blockIdx.x * 4 + wave;
  float a0 = 0, a1 = 0, a2 = 0, a3 = 0;
#pragma unroll
  for (int i = 0; i < 16; ++i) {
    int d = lane + i * 64;
    float h = h2[t * 1024 + d];
    float4 w = ((const float4*)gw)[d];
    a0 += h * w.x; a1 += h * w.y; a2 += h * w.z; a3 += h * w.w;
  }
#pragma unroll
  for (int off = 32; off > 0; off >>= 1) {
    a0 += __shfl_xor(a0, off); a1 += __shfl_xor(a1, off);
    a2 += __shfl_xor(a2, off); a3 += __shfl_xor(a3, off);
  }
  if (lane == 0) {
    float lg[4] = {a0 + gb[0], a1 + gb[1], a2 + gb[2], a3 + gb[3]};
    int i0 = 0;
    for (int e = 1; e < 4; ++e)
      if (lg[e] > lg[i0]) i0 = e;
    int i1 = -1;
    for (int e = 0; e < 4; ++e) {
      if (e == i0) continue;
      if (i1 < 0 || lg[e] > lg[i1]) i1 = e;
    }
    float e1 = __expf(lg[i1] - lg[i0]);
    float p0 = 1.f / (1.f + e1), p1 = e1 / (1.f + e1);
    float o[4] = {0.f, 0.f, 0.f, 0.f};
    o[i0] = p0; o[i1] = p1;
    w4[t * 4 + 0] = o[0]; w4[t * 4 + 1] = o[1];
    w4[t * 4 + 2] = o[2]; w4[t * 4 + 3] = o[3];
  }
}

// per-expert token list, ordered by token id (deterministic). 1 block/expert.
__global__ __launch_bounds__(256) void build_k(const float* __restrict__ w4,
                                               int* __restrict__ idx,
                                               int* __restrict__ cnt) {
  const int e = blockIdx.x;
  const int tid = threadIdx.x;
  const int base = tid * 16;
  unsigned char loc[16];
  int c = 0;
#pragma unroll
  for (int i = 0; i < 16; ++i)
    if (w4[(long)(base + i) * 4 + e] != 0.f) loc[c++] = (unsigned char)i;
  __shared__ int ps[256];
  ps[tid] = c;
  __syncthreads();
  for (int off = 1; off < 256; off <<= 1) {
    int v = (tid >= off) ? ps[tid - off] : 0;
    __syncthreads();
    ps[tid] += v;
    __syncthreads();
  }
  int p = ps[tid] - c;
  for (int i = 0; i < c; ++i) idx[e * 4096 + p + i] = base + (int)loc[i];
  if (tid == 255) cnt[e] = ps[255];
}

extern "C" void kernel_launch(void* const* d_in, const int* in_sizes, int n_in,
                              void* d_out, int out_size, void* d_ws, size_t ws_size,
                              hipStream_t stream) {
  const float* x = (const float*)d_in[0];
  const float* n1w = (const float*)d_in[1];
  const float* n2w = (const float*)d_in[2];
  const float* inpw = (const float*)d_in[3];
  const float* inpb = (const float*)d_in[4];
  const float* convw = (const float*)d_in[5];
  const float* convb = (const float*)d_in[6];
  const float* dtw = (const float*)d_in[7];
  const float* dtb = (const float*)d_in[8];
  const float* bpw = (const float*)d_in[9];
  const float* bpb = (const float*)d_in[10];
  const float* cpw = (const float*)d_in[11];
  const float* cpb = (const float*)d_in[12];
  const float* s2iw = (const float*)d_in[13];
  const float* s2ib = (const float*)d_in[14];
  const float* Dp = (const float*)d_in[15];
  const float* outw = (const float*)d_in[16];
  const float* outb_ = (const float*)d_in[17];
  const float* gatew = (const float*)d_in[18];
  const float* gateb = (const float*)d_in[19];
  const float* ew1 = (const float*)d_in[20];
  const float* eb1 = (const float*)d_in[21];
  const float* ew2 = (const float*)d_in[22];
  const float* eb2 = (const float*)d_in[23];
  float* out = (float*)d_out;

  char* ws = (char*)d_ws;
  size_t off = 0;
  auto alloc = [&](size_t bytes) -> void* {
    void* p = (void*)(ws + off);
    off += (bytes + 255) & ~(size_t)255;
    return p;
  };

  bf16_t* h1b = (bf16_t*)alloc((size_t)NTOK * 1024 * 2);
  bf16_t* inpT = (bf16_t*)alloc((size_t)4096 * 1024 * 2);
  bf16_t* wdtT = (bf16_t*)alloc((size_t)256 * 2048 * 2);
  float* biasdt = (float*)alloc(256 * 4);
  float* ybuf = (float*)alloc((size_t)NTOK * 64 * 4);
  bf16_t* ylnb = (bf16_t*)alloc((size_t)NTOK * 64 * 2);
  bf16_t* s2iT = (bf16_t*)alloc((size_t)2048 * 64 * 2);
  bf16_t* outT = (bf16_t*)alloc((size_t)1024 * 2048 * 2);
  float* x2 = (float*)alloc((size_t)NTOK * 1024 * 4);
  bf16_t* h2b = (bf16_t*)alloc((size_t)NTOK * 1024 * 2);
  float* h2f = (float*)alloc((size_t)NTOK * 1024 * 4);
  float* w4 = (float*)alloc((size_t)NTOK * 4 * 4);
  int* eidx = (int*)alloc((size_t)4 * 4096 * 4);
  int* ecnt = (int*)alloc(4 * 4);
  // union region: mixer temporaries, later reused by MoE temporaries
  const size_t SZ_XZ = (size_t)NTOK * 4096 * 2;   // 32MB
  const size_t SZ_XS = (size_t)NTOK * 2048 * 2;   // 16MB
  const size_t SZ_DT = (size_t)NTOK * 256 * 4;    // 4MB
  const size_t SZ_Z = (size_t)NTOK * 2048 * 2;    // 16MB
  char* reg = (char*)alloc(SZ_XZ + SZ_XS + SZ_DT + SZ_Z);
  bf16_t* xzb = (bf16_t*)reg;
  bf16_t* xsb = (bf16_t*)(reg + SZ_XZ);
  float* dtbc = (float*)(reg + SZ_XZ + SZ_XS);
  bf16_t* zb = (bf16_t*)(reg + SZ_XZ + SZ_XS + SZ_DT);
  bf16_t* ew1T = (bf16_t*)reg;                       // 8MB (aliases dead xzb)
  bf16_t* ew2T = (bf16_t*)(reg + 8388608);           // 8MB
  bf16_t* hidb = (bf16_t*)(reg + 16777216);          // 32MB

  dim3 tb(32, 8);
  hipMemsetAsync(wdtT, 0, (size_t)256 * 2048 * 2, stream);
  dtbias_k<<<1, 256, 0, stream>>>(dtb, bpb, cpb, biasdt);
  tcast_k<<<dim3(128, 32), tb, 0, stream>>>(inpw, inpT, 1024, 4096);
  tcast_k<<<dim3(2, 64), tb, 0, stream>>>(dtw, wdtT, 2048, 64);
  tcast_k<<<dim3(2, 64), tb, 0, stream>>>(bpw, wdtT + (size_t)64 * 2048, 2048, 64);
  tcast_k<<<dim3(2, 64), tb, 0, stream>>>(cpw, wdtT + (size_t)128 * 2048, 2048, 64);
  tcast_k<<<dim3(64, 2), tb, 0, stream>>>(s2iw, s2iT, 64, 2048);
  tcast_k<<<dim3(32, 64), tb, 0, stream>>>(outw, outT, 2048, 1024);

  // ---- mixer ----
  rmsnorm_k<<<NTOK, 256, 0, stream>>>(x, n1w, h1b, nullptr, 0);
  gemm_bt<5, 128><<<dim3(32, 32), 256, 0, stream>>>(h1b, inpT, NTOK, 4096, 1024,
      nullptr, xzb, inpb, nullptr, 0, nullptr, 0, nullptr, 0, nullptr, nullptr,
      nullptr, nullptr, nullptr);
  conv_silu_k<<<(NTOK * 2048) / 256, 256, 0, stream>>>(xzb, convw, convb, xsb);
  gemm_bt<0, 64><<<dim3(4, 32), 256, 0, stream>>>(xsb, wdtT, NTOK, 256, 2048,
      dtbc, nullptr, biasdt, nullptr, 0, nullptr, 0, nullptr, 0, nullptr, nullptr,
      nullptr, nullptr, nullptr);
  scan_k<<<128, 256, 0, stream>>>(dtbc, ybuf);
  ln64_k<<<NTOK / 4, 256, 0, stream>>>(ybuf, ylnb);
  gemm_bt<1, 128><<<dim3(16, 32), 256, 0, stream>>>(ylnb, s2iT, NTOK, 2048, 64,
      nullptr, zb, s2ib, xsb, 2048, xzb + 2048, 4096, nullptr, 0, Dp, nullptr,
      nullptr, nullptr, nullptr);
  gemm_bt<2, 64><<<dim3(16, 32), 256, 0, stream>>>(zb, outT, NTOK, 1024, 2048,
      x2, nullptr, outb_, nullptr, 0, nullptr, 0, x, 1024, nullptr, nullptr, out,
      nullptr, nullptr);

  // ---- MoE (top-2 sparse) ----
  rmsnorm_k<<<NTOK, 256, 0, stream>>>(x2, n2w, h2b, h2f, 1);
  gate_k<<<NTOK / 4, 256, 0, stream>>>(h2f, gatew, gateb, w4);
  build_k<<<4, 256, 0, stream>>>(w4, eidx, ecnt);
  for (int e = 0; e < 4; ++e) {
    tcast_k<<<dim3(128, 32), tb, 0, stream>>>(ew1 + (size_t)e * 1024 * 4096, ew1T, 1024, 4096);
    gemm_bt<3, 128><<<dim3(32, 32), 256, 0, stream>>>(h2b, ew1T, NTOK, 4096, 1024,
        nullptr, hidb, eb1 + (size_t)e * 4096, nullptr, 0, nullptr, 0, nullptr, 0,
        nullptr, nullptr, nullptr, eidx + e * 4096, ecnt + e);
    tcast_k<<<dim3(32, 128), tb, 0, stream>>>(ew2 + (size_t)e * 4096 * 1024, ew2T, 4096, 1024);
    gemm_bt<6, 64><<<dim3(16, 32), 256, 0, stream>>>(hidb, ew2T, NTOK, 1024, 4096,
        out, nullptr, eb2 + (size_t)e * 1024, nullptr, 0, nullptr, 0, nullptr, 0,
        nullptr, w4 + e, nullptr, eidx + e * 4096, ecnt + e);
  }
}

// Round 4
// 748.499 us; speedup vs baseline: 1.5699x; 1.3897x over previous
//
#include <hip/hip_runtime.h>
#include <hip/hip_bf16.h>
#include <math.h>
#include <stdint.h>

#define T_ 2048
#define NTOK 4096
#define MB (1024 * 1024)

typedef unsigned short bf16_t;
typedef __attribute__((ext_vector_type(8))) short short8;
typedef __attribute__((ext_vector_type(4))) float f32x4;
typedef __attribute__((ext_vector_type(4))) unsigned short us4;

__device__ __forceinline__ bf16_t f2bf(float f) {
  unsigned u = __float_as_uint(f);
  u += 0x7fffu + ((u >> 16) & 1u);
  return (bf16_t)(u >> 16);
}
__device__ __forceinline__ float bf2f(bf16_t h) {
  return __uint_as_float(((unsigned)h) << 16);
}
__device__ __forceinline__ float sigm(float x) { return 1.f / (1.f + __expf(-x)); }

__device__ __forceinline__ void gload_lds16(const bf16_t* g, bf16_t* l) {
  __builtin_amdgcn_global_load_lds(
      (const __attribute__((address_space(1))) void*)g,
      (__attribute__((address_space(3))) void*)l, 16, 0, 0);
}

// ---------------------------------------------------------------------------
// bf16 MFMA GEMM: C[M,N] = A[M,K] * BT[N,K]^T, 128xBN tile (BN=128 or 64),
// K-step 64 as two BK=32 sub-buffers. XOR bank swizzle on k-chunks (verified:
// conflicts 4.19M -> 0). Dense modes use XCD patch swizzle for L2 locality.
// Merged-MoE modes (7/8) cover ALL experts in one dispatch: tile->expert via
// meta (cntp), 128-padded concat token list in gidx (pad = -1).
// MODE 0: outf = acc + bias
// MODE 5: outb = bf16(acc + bias)
// MODE 1: outb = bf16((acc+bias + d0[col]*xb0) * sigmoid(xb1))
// MODE 2: v = acc+bias+xf0 -> outf and outf2
// MODE 7: A gathered via gidx; outb(hid)[row] = bf16(gelu(acc+bias_e))
// MODE 8: t=gidx[row]; if t>=0 atomicAdd(outf[t*N+col], w4[t*4+e]*(acc+bias_e))
// ---------------------------------------------------------------------------
template <int MODE, int BN>
__global__ __launch_bounds__(256) void gemm_bt(
    const bf16_t* __restrict__ A, const bf16_t* __restrict__ BT,
    int M, int N, int K,
    float* __restrict__ outf, bf16_t* __restrict__ outb,
    const float* __restrict__ bias,
    const bf16_t* __restrict__ xb0, int xs0,
    const bf16_t* __restrict__ xb1, int xs1,
    const float* __restrict__ xf0, int xfs0,
    const float* __restrict__ d0,
    const float* __restrict__ scale4,
    float* __restrict__ outf2,
    const int* __restrict__ gidx,
    const int* __restrict__ cntp) {
  constexpr int NJ = BN / 32;  // n-tiles per wave (4 or 2)
  __shared__ __align__(16) bf16_t As[2][128 * 32];
  __shared__ __align__(16) bf16_t Bs[2][BN * 32];
  const int tid = threadIdx.x;
  const int wave = tid >> 6;
  const int lane = tid & 63;

  long m0, n0;
  const bf16_t* Bb = BT;
  const float* biasp = bias;
  int eSel = 0;
  if constexpr (MODE == 7 || MODE == 8) {
    const int mt = blockIdx.y, nt = blockIdx.x;
    if (mt >= cntp[0]) return;          // inactive tile
    eSel = cntp[1 + mt] & 3;            // clamp: safe even if hoisted
    m0 = (long)mt * 128;
    n0 = (long)nt * BN;
    Bb = BT + (long)eSel * N * K;
    biasp = bias + (long)eSel * N;
  } else {
    // XCD-aware patch swizzle (id%8 -> XCD assumed; validated by FETCH drop)
    const int tn = gridDim.x, tm = gridDim.y;
    const int id = blockIdx.y * tn + blockIdx.x;
    const int xcd = id & 7;
    const int s = id >> 3;
    const int pm = tm >> 2;
    const int pn = tn >> 1;
    const int mt = (xcd & 3) * pm + (s % pm);
    const int nt = (xcd >> 2) * pn + (s / pm);
    m0 = (long)mt * 128;
    n0 = (long)nt * BN;
  }

  f32x4 acc[4][NJ];
#pragma unroll
  for (int i = 0; i < 4; ++i)
#pragma unroll
    for (int j = 0; j < NJ; ++j) acc[i][j] = f32x4{0.f, 0.f, 0.f, 0.f};

  const int rowL = tid >> 2;  // 0..63
  const int qL = tid & 3;
  const int ks = (qL ^ ((rowL >> 1) & 3)) * 8;  // XOR-swizzled k-chunk
  long r0 = m0 + rowL, r1 = m0 + rowL + 64;
  if constexpr (MODE == 7) {
    int t0k = gidx[r0], t1k = gidx[r1];
    r0 = (t0k < 0) ? 0 : t0k;
    r1 = (t1k < 0) ? 0 : t1k;
  }
  const bf16_t* pA0 = A + r0 * (long)K + ks;
  const bf16_t* pA1 = A + r1 * (long)K + ks;
  const bf16_t* pB0 = Bb + (n0 + rowL) * (long)K + ks;
  const bf16_t* pB1 = Bb + (n0 + rowL + 64) * (long)K + ks;  // BN=128 only
  bf16_t* lA0 = As[0] + wave * 512;
  bf16_t* lB0 = Bs[0] + wave * 512;
  bf16_t* lA1 = As[1] + wave * 512;
  bf16_t* lB1 = Bs[1] + wave * 512;

  const int wm = (wave & 1) * 64;
  const int wn = (wave >> 1) * (BN / 2);
  const int lm = lane & 15;
  const int kq = ((lane >> 4) ^ ((lm >> 1) & 3)) * 8;  // swizzled read offset

  for (int k0 = 0; k0 < K; k0 += 64) {
    gload_lds16(pA0 + k0, lA0);
    gload_lds16(pA1 + k0, lA0 + 2048);
    gload_lds16(pB0 + k0, lB0);
    if constexpr (BN == 128) gload_lds16(pB1 + k0, lB0 + 2048);
    gload_lds16(pA0 + k0 + 32, lA1);
    gload_lds16(pA1 + k0 + 32, lA1 + 2048);
    gload_lds16(pB0 + k0 + 32, lB1);
    if constexpr (BN == 128) gload_lds16(pB1 + k0 + 32, lB1 + 2048);
    __syncthreads();
#pragma unroll
    for (int h = 0; h < 2; ++h) {
      short8 af[4], bfr[NJ];
#pragma unroll
      for (int i = 0; i < 4; ++i)
        af[i] = *(const short8*)(As[h] + (wm + i * 16 + lm) * 32 + kq);
#pragma unroll
      for (int j = 0; j < NJ; ++j)
        bfr[j] = *(const short8*)(Bs[h] + (wn + j * 16 + lm) * 32 + kq);
#pragma unroll
      for (int i = 0; i < 4; ++i)
#pragma unroll
        for (int j = 0; j < NJ; ++j)
          acc[i][j] = __builtin_amdgcn_mfma_f32_16x16x32_bf16(af[i], bfr[j], acc[i][j], 0, 0, 0);
    }
    __syncthreads();
  }

  const int er = (lane >> 4) * 4;  // C/D: row=(lane>>4)*4+reg, col=lane&15
  const int ec = lane & 15;
#pragma unroll
  for (int i = 0; i < 4; ++i) {
#pragma unroll
    for (int j = 0; j < NJ; ++j) {
#pragma unroll
      for (int r = 0; r < 4; ++r) {
        long row = m0 + wm + i * 16 + er + r;
        long col = n0 + wn + j * 16 + ec;
        float v = acc[i][j][r] + biasp[col];
        if constexpr (MODE == 0) {
          outf[row * N + col] = v;
        } else if constexpr (MODE == 5) {
          outb[row * N + col] = f2bf(v);
        } else if constexpr (MODE == 1) {
          float xm = bf2f(xb0[row * (long)xs0 + col]);
          float g = bf2f(xb1[row * (long)xs1 + col]);
          v = (v + d0[col] * xm) * sigm(g);
          outb[row * N + col] = f2bf(v);
        } else if constexpr (MODE == 2) {
          v += xf0[row * (long)xfs0 + col];
          outf[row * N + col] = v;
          outf2[row * N + col] = v;
        } else if constexpr (MODE == 7) {
          v = 0.5f * v * (1.f + erff(v * 0.70710678118654752f));
          outb[row * N + col] = f2bf(v);   // row = concat row (pad rows harmless)
        } else if constexpr (MODE == 8) {
          int t = gidx[row];
          if (t >= 0)
            unsafeAtomicAdd(outf + (long)t * N + col, scale4[t * 4 + eSel] * v);
        }
      }
    }
  }
}

// fp32 [R,C] -> bf16 [C,R]  (weights to B^T layout)
__global__ __launch_bounds__(256) void tcast_k(const float* __restrict__ in,
                                               bf16_t* __restrict__ out, int R, int C) {
  __shared__ float tile[32][33];
  const int tx = threadIdx.x, ty = threadIdx.y;
  const long c0 = (long)blockIdx.x * 32, r0 = (long)blockIdx.y * 32;
#pragma unroll
  for (int i = 0; i < 4; ++i) {
    int r = ty + i * 8;
    tile[r][tx] = in[(r0 + r) * (long)C + c0 + tx];
  }
  __syncthreads();
#pragma unroll
  for (int i = 0; i < 4; ++i) {
    int r = ty + i * 8;
    out[(c0 + r) * (long)R + r0 + tx] = f2bf(tile[tx][r]);
  }
}

__global__ void dtbias_k(const float* __restrict__ dtb, const float* __restrict__ bpb,
                         const float* __restrict__ cpb, float* __restrict__ out) {
  int i = threadIdx.x;
  float v = 0.f;
  if (i < 64) v = dtb[i];
  else if (i < 128) v = bpb[i - 64];
  else if (i < 192) v = cpb[i - 128];
  out[i] = v;
}

// rmsnorm over D=1024, one block per row; bf16 out
__global__ __launch_bounds__(256) void rmsnorm_k(const float* __restrict__ x,
                                                 const float* __restrict__ w,
                                                 bf16_t* __restrict__ ob) {
  const long row = blockIdx.x;
  const int tid = threadIdx.x;
  const int wave = tid >> 6, lane = tid & 63;
  const float4 v = ((const float4*)(x + row * 1024))[tid];
  float ss = v.x * v.x + v.y * v.y + v.z * v.z + v.w * v.w;
#pragma unroll
  for (int off = 32; off > 0; off >>= 1) ss += __shfl_down(ss, off);
  __shared__ float sred[4];
  if (lane == 0) sred[wave] = ss;
  __syncthreads();
  float tot = sred[0] + sred[1] + sred[2] + sred[3];
  float nr = rsqrtf(tot * (1.f / 1024.f) + 1e-6f);
  const float4 wv = ((const float4*)w)[tid];
  us4 o;
  o.x = f2bf(v.x * nr * wv.x);
  o.y = f2bf(v.y * nr * wv.y);
  o.z = f2bf(v.z * nr * wv.z);
  o.w = f2bf(v.w * nr * wv.w);
  ((us4*)ob)[row * 256 + tid] = o;
}

// causal depthwise conv (K=3) + bias + silu, bf16 in/out
__global__ __launch_bounds__(256) void conv_silu_k(const bf16_t* __restrict__ xz,
                                                   const float* __restrict__ cw,
                                                   const float* __restrict__ cb,
                                                   bf16_t* __restrict__ xs) {
  long idx = (long)blockIdx.x * 256 + threadIdx.x;  // < 4096*2048
  int c = (int)(idx & 2047);
  long row = idx >> 11;
  int t = (int)(row & 2047);
  const bf16_t* p = xz + row * 4096 + c;
  float v = bf2f(p[0]) * cw[c * 3 + 2];
  if (t >= 1) v += bf2f(*(p - 4096)) * cw[c * 3 + 1];
  if (t >= 2) v += bf2f(*(p - 8192)) * cw[c * 3 + 0];
  v += cb[c];
  v = v * sigm(v);
  xs[idx] = f2bf(v);
}

// parallel linear-recurrence scan: one block per (b, s) channel
__global__ __launch_bounds__(256) void scan_k(const float* __restrict__ dtbc,
                                              float* __restrict__ y) {
  const int bid = blockIdx.x;  // 0..127
  const int b = bid >> 6, s = bid & 63;
  const int tid = threadIdx.x;
  const float* base = dtbc + (long)b * T_ * 256;
  const int t0 = tid * 8;
  float A = 1.f, U = 0.f;
#pragma unroll
  for (int i = 0; i < 8; ++i) {
    const float* r = base + (long)(t0 + i) * 256;
    float dt = sigm(r[s]);
    float bv = r[64 + s];
    U = (1.f - dt) * U + dt * bv;
    A = (1.f - dt) * A;
  }
  __shared__ float sA[256], sU[256];
  sA[tid] = A; sU[tid] = U;
  __syncthreads();
  for (int off = 1; off < 256; off <<= 1) {
    float pA = 1.f, pU = 0.f;
    if (tid >= off) { pA = sA[tid - off]; pU = sU[tid - off]; }
    __syncthreads();
    U = A * pU + U;
    A = A * pA;
    sA[tid] = A; sU[tid] = U;
    __syncthreads();
  }
  float st = (tid == 0) ? 0.f : sU[tid - 1];
#pragma unroll
  for (int i = 0; i < 8; ++i) {
    const float* r = base + (long)(t0 + i) * 256;
    float dt = sigm(r[s]);
    float bv = r[64 + s];
    st = (1.f - dt) * st + dt * bv;
    y[((long)b * T_ + t0 + i) * 64 + s] = r[128 + s] * st;
  }
}

// layernorm over S=64, one wave per row
__global__ __launch_bounds__(256) void ln64_k(const float* __restrict__ y,
                                              bf16_t* __restrict__ yb) {
  const int tid = threadIdx.x;
  const int wave = tid >> 6, lane = tid & 63;
  const long row = (long)blockIdx.x * 4 + wave;
  float v = y[row * 64 + lane];
  float m = v;
#pragma unroll
  for (int off = 32; off > 0; off >>= 1) m += __shfl_xor(m, off);
  m *= (1.f / 64.f);
  float d = v - m;
  float var = d * d;
#pragma unroll
  for (int off = 32; off > 0; off >>= 1) var += __shfl_xor(var, off);
  var *= (1.f / 64.f);
  yb[row * 64 + lane] = f2bf(d * rsqrtf(var + 1e-5f));
}

// router with fused rmsnorm: logits = rsqrt(mean(x^2)+eps) * ((x*nw) @ gw) + gb
// top-2 softmax -> per-expert combine weights [tok][4]
__global__ __launch_bounds__(256) void gate_k(const float* __restrict__ x2,
                                              const float* __restrict__ nw,
                                              const float* __restrict__ gw,
                                              const float* __restrict__ gb,
                                              float* __restrict__ w4) {
  const int tid = threadIdx.x;
  const int wave = tid >> 6, lane = tid & 63;
  const long t = (long)blockIdx.x * 4 + wave;
  float a0 = 0, a1 = 0, a2 = 0, a3 = 0, ssq = 0;
#pragma unroll
  for (int i = 0; i < 16; ++i) {
    int d = lane + i * 64;
    float xv = x2[t * 1024 + d];
    ssq += xv * xv;
    float h = xv * nw[d];
    float4 w = ((const float4*)gw)[d];
    a0 += h * w.x; a1 += h * w.y; a2 += h * w.z; a3 += h * w.w;
  }
#pragma unroll
  for (int off = 32; off > 0; off >>= 1) {
    a0 += __shfl_xor(a0, off); a1 += __shfl_xor(a1, off);
    a2 += __shfl_xor(a2, off); a3 += __shfl_xor(a3, off);
    ssq += __shfl_xor(ssq, off);
  }
  if (lane == 0) {
    float nr = rsqrtf(ssq * (1.f / 1024.f) + 1e-6f);
    float lg[4] = {a0 * nr + gb[0], a1 * nr + gb[1], a2 * nr + gb[2], a3 * nr + gb[3]};
    int i0 = 0;
    for (int e = 1; e < 4; ++e)
      if (lg[e] > lg[i0]) i0 = e;
    int i1 = -1;
    for (int e = 0; e < 4; ++e) {
      if (e == i0) continue;
      if (i1 < 0 || lg[e] > lg[i1]) i1 = e;
    }
    float e1 = __expf(lg[i1] - lg[i0]);
    float p0 = 1.f / (1.f + e1), p1 = e1 / (1.f + e1);
    float o[4] = {0.f, 0.f, 0.f, 0.f};
    o[i0] = p0; o[i1] = p1;
    w4[t * 4 + 0] = o[0]; w4[t * 4 + 1] = o[1];
    w4[t * 4 + 2] = o[2]; w4[t * 4 + 3] = o[3];
  }
}

// Build 128-padded concat token list across experts + tile->expert table.
// Single block of 256 threads. cidx pad = -1. meta[0]=nTiles, meta[1+t]=expert.
__global__ __launch_bounds__(256) void build2_k(const float* __restrict__ w4,
                                                int* __restrict__ cidx,
                                                int* __restrict__ meta) {
  __shared__ int ps[256];
  __shared__ int tbase_s;
  const int tid = threadIdx.x;
  if (tid == 0) tbase_s = 0;
  __syncthreads();
  for (int e = 0; e < 4; ++e) {
    const int base = tid * 16;
    unsigned char loc[16];
    int c = 0;
#pragma unroll
    for (int i = 0; i < 16; ++i)
      if (w4[(long)(base + i) * 4 + e] != 0.f) loc[c++] = (unsigned char)i;
    ps[tid] = c;
    __syncthreads();
    for (int off = 1; off < 256; off <<= 1) {
      int v = (tid >= off) ? ps[tid - off] : 0;
      __syncthreads();
      ps[tid] += v;
      __syncthreads();
    }
    const int total = ps[255];
    const int p = ps[tid] - c;
    const int tbase = tbase_s;
    const int rowbase = tbase * 128;
    for (int i = 0; i < c; ++i) cidx[rowbase + p + i] = base + (int)loc[i];
    const int tiles = (total + 127) >> 7;
    for (int j = total + tid; j < tiles * 128; j += 256) cidx[rowbase + j] = -1;
    for (int j = tid; j < tiles; j += 256) meta[1 + tbase + j] = e;
    __syncthreads();
    if (tid == 0) tbase_s = tbase + tiles;
    __syncthreads();
  }
  if (tid == 0) meta[0] = tbase_s;
}

extern "C" void kernel_launch(void* const* d_in, const int* in_sizes, int n_in,
                              void* d_out, int out_size, void* d_ws, size_t ws_size,
                              hipStream_t stream) {
  const float* x = (const float*)d_in[0];
  const float* n1w = (const float*)d_in[1];
  const float* n2w = (const float*)d_in[2];
  const float* inpw = (const float*)d_in[3];
  const float* inpb = (const float*)d_in[4];
  const float* convw = (const float*)d_in[5];
  const float* convb = (const float*)d_in[6];
  const float* dtw = (const float*)d_in[7];
  const float* dtb = (const float*)d_in[8];
  const float* bpw = (const float*)d_in[9];
  const float* bpb = (const float*)d_in[10];
  const float* cpw = (const float*)d_in[11];
  const float* cpb = (const float*)d_in[12];
  const float* s2iw = (const float*)d_in[13];
  const float* s2ib = (const float*)d_in[14];
  const float* Dp = (const float*)d_in[15];
  const float* outw = (const float*)d_in[16];
  const float* outb_ = (const float*)d_in[17];
  const float* gatew = (const float*)d_in[18];
  const float* gateb = (const float*)d_in[19];
  const float* ew1 = (const float*)d_in[20];
  const float* eb1 = (const float*)d_in[21];
  const float* ew2 = (const float*)d_in[22];
  const float* eb2 = (const float*)d_in[23];
  float* out = (float*)d_out;

  char* ws = (char*)d_ws;
  size_t off = 0;
  auto alloc = [&](size_t bytes) -> void* {
    void* p = (void*)(ws + off);
    off += (bytes + 255) & ~(size_t)255;
    return p;
  };

  float* biasdt = (float*)alloc(256 * 4);
  float* ybuf = (float*)alloc((size_t)NTOK * 64 * 4);
  bf16_t* ylnb = (bf16_t*)alloc((size_t)NTOK * 64 * 2);
  float* x2 = (float*)alloc((size_t)NTOK * 1024 * 4);
  bf16_t* h2b = (bf16_t*)alloc((size_t)NTOK * 1024 * 2);
  float* w4 = (float*)alloc((size_t)NTOK * 4 * 4);
  int* cidx = (int*)alloc((size_t)68 * 128 * 4);
  int* meta = (int*)alloc(128 * 4);

  // Aliased region. Mixer phase:   [0,32M) xzb | [32M,48M) xsb | [48M,52M) dtbc
  //                                 [52M,68M) zb
  // Weights (die before clobber):  [64M,72M) inpT | [72M,76M) outT | [76M,84M) h1b
  //                                 [84M,85M) wdtT | [85M,85.25M) s2iT
  // MoE phase (after mixer):       [0,32M) w1T | [32M,64M) w2T | [64M,~135M) hidb
  const size_t REG_SZ = 64 * (size_t)MB + (size_t)8704 * 4096 * 2;
  char* reg = (char*)alloc(REG_SZ);
  bf16_t* xzb = (bf16_t*)reg;
  bf16_t* xsb = (bf16_t*)(reg + 32 * (size_t)MB);
  float* dtbc = (float*)(reg + 48 * (size_t)MB);
  bf16_t* zb = (bf16_t*)(reg + 52 * (size_t)MB);
  bf16_t* inpT = (bf16_t*)(reg + 64 * (size_t)MB);
  bf16_t* outT = (bf16_t*)(reg + 72 * (size_t)MB);
  bf16_t* h1b = (bf16_t*)(reg + 76 * (size_t)MB);
  bf16_t* wdtT = (bf16_t*)(reg + 84 * (size_t)MB);
  bf16_t* s2iT = (bf16_t*)(reg + 85 * (size_t)MB);
  bf16_t* w1T = (bf16_t*)reg;
  bf16_t* w2T = (bf16_t*)(reg + 32 * (size_t)MB);
  bf16_t* hidb = (bf16_t*)(reg + 64 * (size_t)MB);

  dim3 tb(32, 8);
  hipMemsetAsync(wdtT, 0, (size_t)256 * 2048 * 2, stream);
  dtbias_k<<<1, 256, 0, stream>>>(dtb, bpb, cpb, biasdt);
  tcast_k<<<dim3(128, 32), tb, 0, stream>>>(inpw, inpT, 1024, 4096);
  tcast_k<<<dim3(2, 64), tb, 0, stream>>>(dtw, wdtT, 2048, 64);
  tcast_k<<<dim3(2, 64), tb, 0, stream>>>(bpw, wdtT + (size_t)64 * 2048, 2048, 64);
  tcast_k<<<dim3(2, 64), tb, 0, stream>>>(cpw, wdtT + (size_t)128 * 2048, 2048, 64);
  tcast_k<<<dim3(64, 2), tb, 0, stream>>>(s2iw, s2iT, 64, 2048);
  tcast_k<<<dim3(32, 64), tb, 0, stream>>>(outw, outT, 2048, 1024);

  // ---- mixer ----
  rmsnorm_k<<<NTOK, 256, 0, stream>>>(x, n1w, h1b);
  gemm_bt<5, 128><<<dim3(32, 32), 256, 0, stream>>>(h1b, inpT, NTOK, 4096, 1024,
      nullptr, xzb, inpb, nullptr, 0, nullptr, 0, nullptr, 0, nullptr, nullptr,
      nullptr, nullptr, nullptr);
  conv_silu_k<<<(NTOK * 2048) / 256, 256, 0, stream>>>(xzb, convw, convb, xsb);
  gemm_bt<0, 64><<<dim3(4, 32), 256, 0, stream>>>(xsb, wdtT, NTOK, 256, 2048,
      dtbc, nullptr, biasdt, nullptr, 0, nullptr, 0, nullptr, 0, nullptr, nullptr,
      nullptr, nullptr, nullptr);
  scan_k<<<128, 256, 0, stream>>>(dtbc, ybuf);
  ln64_k<<<NTOK / 4, 256, 0, stream>>>(ybuf, ylnb);
  gemm_bt<1, 128><<<dim3(16, 32), 256, 0, stream>>>(ylnb, s2iT, NTOK, 2048, 64,
      nullptr, zb, s2ib, xsb, 2048, xzb + 2048, 4096, nullptr, 0, Dp, nullptr,
      nullptr, nullptr, nullptr);
  gemm_bt<2, 64><<<dim3(16, 32), 256, 0, stream>>>(zb, outT, NTOK, 1024, 2048,
      x2, nullptr, outb_, nullptr, 0, nullptr, 0, x, 1024, nullptr, nullptr, out,
      nullptr, nullptr);

  // ---- MoE (top-2 sparse, merged across experts) ----
  // expert weight transposes clobber mixer temps (all dead after MODE 2)
  for (int e = 0; e < 4; ++e) {
    tcast_k<<<dim3(128, 32), tb, 0, stream>>>(ew1 + (size_t)e * 1024 * 4096,
        w1T + (size_t)e * 4096 * 1024, 1024, 4096);
    tcast_k<<<dim3(32, 128), tb, 0, stream>>>(ew2 + (size_t)e * 4096 * 1024,
        w2T + (size_t)e * 1024 * 4096, 4096, 1024);
  }
  rmsnorm_k<<<NTOK, 256, 0, stream>>>(x2, n2w, h2b);
  gate_k<<<NTOK / 4, 256, 0, stream>>>(x2, n2w, gatew, gateb, w4);
  build2_k<<<1, 256, 0, stream>>>(w4, cidx, meta);
  // all-expert W1 + gelu -> hidb (concat rows)
  gemm_bt<7, 128><<<dim3(32, 68), 256, 0, stream>>>(h2b, w1T, 8704, 4096, 1024,
      nullptr, hidb, eb1, nullptr, 0, nullptr, 0, nullptr, 0, nullptr, nullptr,
      nullptr, cidx, meta);
  // all-expert W2, scatter-accumulate into out
  gemm_bt<8, 64><<<dim3(16, 68), 256, 0, stream>>>(hidb, w2T, 8704, 1024, 4096,
      out, nullptr, eb2, nullptr, 0, nullptr, 0, nullptr, 0, nullptr, w4,
      nullptr, cidx, meta);
}

// Round 5
// 723.546 us; speedup vs baseline: 1.6240x; 1.0345x over previous
//
#include <hip/hip_runtime.h>
#include <hip/hip_bf16.h>
#include <math.h>
#include <stdint.h>

#define T_ 2048
#define NTOK 4096
#define MB (1024 * 1024)

typedef unsigned short bf16_t;
typedef __attribute__((ext_vector_type(8))) short short8;
typedef __attribute__((ext_vector_type(4))) float f32x4;
typedef __attribute__((ext_vector_type(4))) unsigned short us4;

__device__ __forceinline__ bf16_t f2bf(float f) {
  unsigned u = __float_as_uint(f);
  u += 0x7fffu + ((u >> 16) & 1u);
  return (bf16_t)(u >> 16);
}
__device__ __forceinline__ float bf2f(bf16_t h) {
  return __uint_as_float(((unsigned)h) << 16);
}
__device__ __forceinline__ float sigm(float x) { return 1.f / (1.f + __expf(-x)); }

__device__ __forceinline__ void gload_lds16(const bf16_t* g, bf16_t* l) {
  __builtin_amdgcn_global_load_lds(
      (const __attribute__((address_space(1))) void*)g,
      (__attribute__((address_space(3))) void*)l, 16, 0, 0);
}

// ---------------------------------------------------------------------------
// bf16 MFMA GEMM: C[M,N] = A[M,K] * BT[N,K]^T, 128xBN tile (BN=128 or 64),
// K-step 64 as two BK=32 sub-buffers. XOR bank swizzle on k-chunks (verified:
// conflicts 4.19M -> 0). Dense modes: XCD patch swizzle (verified FETCH
// 139->33 MB). MoE modes 7/8: one dispatch covers all experts; tile->expert
// via meta; patch swizzle = m-quarter x n-half, n-fastest inner order so each
// A-tile is read by 2 XCDs with temporally-adjacent consumers.
// MODE 0: outf = acc + bias
// MODE 5: outb = bf16(acc + bias)
// MODE 1: outb = bf16((acc+bias + d0[col]*xb0) * sigmoid(xb1))
// MODE 2: v = acc+bias+xf0 -> outf and outf2
// MODE 7: A pre-packed (concat rows); outb = bf16(gelu(acc+bias_e))
// MODE 8: t=gidx[row]; if t>=0 atomicAdd(outf[t*N+col], w4[t*4+e]*(acc+bias_e))
// ---------------------------------------------------------------------------
template <int MODE, int BN>
__global__ __launch_bounds__(256) void gemm_bt(
    const bf16_t* __restrict__ A, const bf16_t* __restrict__ BT,
    int M, int N, int K,
    float* __restrict__ outf, bf16_t* __restrict__ outb,
    const float* __restrict__ bias,
    const bf16_t* __restrict__ xb0, int xs0,
    const bf16_t* __restrict__ xb1, int xs1,
    const float* __restrict__ xf0, int xfs0,
    const float* __restrict__ d0,
    const float* __restrict__ scale4,
    float* __restrict__ outf2,
    const int* __restrict__ gidx,
    const int* __restrict__ cntp) {
  constexpr int NJ = BN / 32;  // n-tiles per wave (4 or 2)
  __shared__ __align__(16) bf16_t As[2][128 * 32];
  __shared__ __align__(16) bf16_t Bs[2][BN * 32];
  const int tid = threadIdx.x;
  const int wave = tid >> 6;
  const int lane = tid & 63;

  long m0, n0;
  const bf16_t* Bb = BT;
  const float* biasp = bias;
  int eSel = 0;
  if constexpr (MODE == 7 || MODE == 8) {
    const int tn = gridDim.x, tm = gridDim.y;
    const int id = blockIdx.y * tn + blockIdx.x;
    const int xcd = id & 7;
    const int s = id >> 3;
    const int pm = (tm + 3) >> 2;       // 17
    const int pn = tn >> 1;             // 16 (M7) / 8 (M8)
    const int mt = (xcd & 3) * pm + s / pn;   // n-fastest within patch
    const int nt = (xcd >> 2) * pn + s % pn;
    if (mt >= cntp[0]) return;          // inactive tile
    eSel = cntp[1 + mt] & 3;            // clamp: safe even if hoisted
    m0 = (long)mt * 128;
    n0 = (long)nt * BN;
    Bb = BT + (long)eSel * N * K;
    biasp = bias + (long)eSel * N;
  } else {
    // XCD-aware patch swizzle (id%8 -> XCD; validated by FETCH drop)
    const int tn = gridDim.x, tm = gridDim.y;
    const int id = blockIdx.y * tn + blockIdx.x;
    const int xcd = id & 7;
    const int s = id >> 3;
    const int pm = tm >> 2;
    const int pn = tn >> 1;
    const int mt = (xcd & 3) * pm + (s % pm);
    const int nt = (xcd >> 2) * pn + (s / pm);
    m0 = (long)mt * 128;
    n0 = (long)nt * BN;
  }

  f32x4 acc[4][NJ];
#pragma unroll
  for (int i = 0; i < 4; ++i)
#pragma unroll
    for (int j = 0; j < NJ; ++j) acc[i][j] = f32x4{0.f, 0.f, 0.f, 0.f};

  const int rowL = tid >> 2;  // 0..63
  const int qL = tid & 3;
  const int ks = (qL ^ ((rowL >> 1) & 3)) * 8;  // XOR-swizzled k-chunk
  const bf16_t* pA0 = A + (m0 + rowL) * (long)K + ks;
  const bf16_t* pA1 = A + (m0 + rowL + 64) * (long)K + ks;
  const bf16_t* pB0 = Bb + (n0 + rowL) * (long)K + ks;
  const bf16_t* pB1 = Bb + (n0 + rowL + 64) * (long)K + ks;  // BN=128 only
  bf16_t* lA0 = As[0] + wave * 512;
  bf16_t* lB0 = Bs[0] + wave * 512;
  bf16_t* lA1 = As[1] + wave * 512;
  bf16_t* lB1 = Bs[1] + wave * 512;

  const int wm = (wave & 1) * 64;
  const int wn = (wave >> 1) * (BN / 2);
  const int lm = lane & 15;
  const int kq = ((lane >> 4) ^ ((lm >> 1) & 3)) * 8;  // swizzled read offset

  for (int k0 = 0; k0 < K; k0 += 64) {
    gload_lds16(pA0 + k0, lA0);
    gload_lds16(pA1 + k0, lA0 + 2048);
    gload_lds16(pB0 + k0, lB0);
    if constexpr (BN == 128) gload_lds16(pB1 + k0, lB0 + 2048);
    gload_lds16(pA0 + k0 + 32, lA1);
    gload_lds16(pA1 + k0 + 32, lA1 + 2048);
    gload_lds16(pB0 + k0 + 32, lB1);
    if constexpr (BN == 128) gload_lds16(pB1 + k0 + 32, lB1 + 2048);
    __syncthreads();
#pragma unroll
    for (int h = 0; h < 2; ++h) {
      short8 af[4], bfr[NJ];
#pragma unroll
      for (int i = 0; i < 4; ++i)
        af[i] = *(const short8*)(As[h] + (wm + i * 16 + lm) * 32 + kq);
#pragma unroll
      for (int j = 0; j < NJ; ++j)
        bfr[j] = *(const short8*)(Bs[h] + (wn + j * 16 + lm) * 32 + kq);
#pragma unroll
      for (int i = 0; i < 4; ++i)
#pragma unroll
        for (int j = 0; j < NJ; ++j)
          acc[i][j] = __builtin_amdgcn_mfma_f32_16x16x32_bf16(af[i], bfr[j], acc[i][j], 0, 0, 0);
    }
    __syncthreads();
  }

  const int er = (lane >> 4) * 4;  // C/D: row=(lane>>4)*4+reg, col=lane&15
  const int ec = lane & 15;
#pragma unroll
  for (int i = 0; i < 4; ++i) {
#pragma unroll
    for (int j = 0; j < NJ; ++j) {
#pragma unroll
      for (int r = 0; r < 4; ++r) {
        long row = m0 + wm + i * 16 + er + r;
        long col = n0 + wn + j * 16 + ec;
        float v = acc[i][j][r] + biasp[col];
        if constexpr (MODE == 0) {
          outf[row * N + col] = v;
        } else if constexpr (MODE == 5) {
          outb[row * N + col] = f2bf(v);
        } else if constexpr (MODE == 1) {
          float xm = bf2f(xb0[row * (long)xs0 + col]);
          float g = bf2f(xb1[row * (long)xs1 + col]);
          v = (v + d0[col] * xm) * sigm(g);
          outb[row * N + col] = f2bf(v);
        } else if constexpr (MODE == 2) {
          v += xf0[row * (long)xfs0 + col];
          outf[row * N + col] = v;
          outf2[row * N + col] = v;
        } else if constexpr (MODE == 7) {
          v = 0.5f * v * (1.f + erff(v * 0.70710678118654752f));
          outb[row * N + col] = f2bf(v);   // concat row (pad rows harmless)
        } else if constexpr (MODE == 8) {
          int t = gidx[row];
          if (t >= 0)
            unsafeAtomicAdd(outf + (long)t * N + col, scale4[t * 4 + eSel] * v);
        }
      }
    }
  }
}

// fp32 [R,C] -> bf16 [C,R]; batched over blockIdx.z with strides
__global__ __launch_bounds__(256) void tcast_k(const float* __restrict__ in,
                                               bf16_t* __restrict__ out, int R, int C,
                                               long inz, long outz) {
  __shared__ float tile[32][33];
  const int tx = threadIdx.x, ty = threadIdx.y;
  const long c0 = (long)blockIdx.x * 32, r0 = (long)blockIdx.y * 32;
  in += (long)blockIdx.z * inz;
  out += (long)blockIdx.z * outz;
#pragma unroll
  for (int i = 0; i < 4; ++i) {
    int r = ty + i * 8;
    tile[r][tx] = in[(r0 + r) * (long)C + c0 + tx];
  }
  __syncthreads();
#pragma unroll
  for (int i = 0; i < 4; ++i) {
    int r = ty + i * 8;
    out[(c0 + r) * (long)R + r0 + tx] = f2bf(tile[tx][r]);
  }
}

__global__ void dtbias_k(const float* __restrict__ dtb, const float* __restrict__ bpb,
                         const float* __restrict__ cpb, float* __restrict__ out) {
  int i = threadIdx.x;
  float v = 0.f;
  if (i < 64) v = dtb[i];
  else if (i < 128) v = bpb[i - 64];
  else if (i < 192) v = cpb[i - 128];
  out[i] = v;
}

// rmsnorm over D=1024, one block per row; bf16 out
__global__ __launch_bounds__(256) void rmsnorm_k(const float* __restrict__ x,
                                                 const float* __restrict__ w,
                                                 bf16_t* __restrict__ ob) {
  const long row = blockIdx.x;
  const int tid = threadIdx.x;
  const int wave = tid >> 6, lane = tid & 63;
  const float4 v = ((const float4*)(x + row * 1024))[tid];
  float ss = v.x * v.x + v.y * v.y + v.z * v.z + v.w * v.w;
#pragma unroll
  for (int off = 32; off > 0; off >>= 1) ss += __shfl_down(ss, off);
  __shared__ float sred[4];
  if (lane == 0) sred[wave] = ss;
  __syncthreads();
  float tot = sred[0] + sred[1] + sred[2] + sred[3];
  float nr = rsqrtf(tot * (1.f / 1024.f) + 1e-6f);
  const float4 wv = ((const float4*)w)[tid];
  us4 o;
  o.x = f2bf(v.x * nr * wv.x);
  o.y = f2bf(v.y * nr * wv.y);
  o.z = f2bf(v.z * nr * wv.z);
  o.w = f2bf(v.w * nr * wv.w);
  ((us4*)ob)[row * 256 + tid] = o;
}

// causal depthwise conv (K=3) + bias + silu, bf16 in/out
__global__ __launch_bounds__(256) void conv_silu_k(const bf16_t* __restrict__ xz,
                                                   const float* __restrict__ cw,
                                                   const float* __restrict__ cb,
                                                   bf16_t* __restrict__ xs) {
  long idx = (long)blockIdx.x * 256 + threadIdx.x;  // < 4096*2048
  int c = (int)(idx & 2047);
  long row = idx >> 11;
  int t = (int)(row & 2047);
  const bf16_t* p = xz + row * 4096 + c;
  float v = bf2f(p[0]) * cw[c * 3 + 2];
  if (t >= 1) v += bf2f(*(p - 4096)) * cw[c * 3 + 1];
  if (t >= 2) v += bf2f(*(p - 8192)) * cw[c * 3 + 0];
  v += cb[c];
  v = v * sigm(v);
  xs[idx] = f2bf(v);
}

// parallel linear-recurrence scan: one block per (b, s) channel
__global__ __launch_bounds__(256) void scan_k(const float* __restrict__ dtbc,
                                              float* __restrict__ y) {
  const int bid = blockIdx.x;  // 0..127
  const int b = bid >> 6, s = bid & 63;
  const int tid = threadIdx.x;
  const float* base = dtbc + (long)b * T_ * 256;
  const int t0 = tid * 8;
  float A = 1.f, U = 0.f;
#pragma unroll
  for (int i = 0; i < 8; ++i) {
    const float* r = base + (long)(t0 + i) * 256;
    float dt = sigm(r[s]);
    float bv = r[64 + s];
    U = (1.f - dt) * U + dt * bv;
    A = (1.f - dt) * A;
  }
  __shared__ float sA[256], sU[256];
  sA[tid] = A; sU[tid] = U;
  __syncthreads();
  for (int off = 1; off < 256; off <<= 1) {
    float pA = 1.f, pU = 0.f;
    if (tid >= off) { pA = sA[tid - off]; pU = sU[tid - off]; }
    __syncthreads();
    U = A * pU + U;
    A = A * pA;
    sA[tid] = A; sU[tid] = U;
    __syncthreads();
  }
  float st = (tid == 0) ? 0.f : sU[tid - 1];
#pragma unroll
  for (int i = 0; i < 8; ++i) {
    const float* r = base + (long)(t0 + i) * 256;
    float dt = sigm(r[s]);
    float bv = r[64 + s];
    st = (1.f - dt) * st + dt * bv;
    y[((long)b * T_ + t0 + i) * 64 + s] = r[128 + s] * st;
  }
}

// layernorm over S=64, one wave per row
__global__ __launch_bounds__(256) void ln64_k(const float* __restrict__ y,
                                              bf16_t* __restrict__ yb) {
  const int tid = threadIdx.x;
  const int wave = tid >> 6, lane = tid & 63;
  const long row = (long)blockIdx.x * 4 + wave;
  float v = y[row * 64 + lane];
  float m = v;
#pragma unroll
  for (int off = 32; off > 0; off >>= 1) m += __shfl_xor(m, off);
  m *= (1.f / 64.f);
  float d = v - m;
  float var = d * d;
#pragma unroll
  for (int off = 32; off > 0; off >>= 1) var += __shfl_xor(var, off);
  var *= (1.f / 64.f);
  yb[row * 64 + lane] = f2bf(d * rsqrtf(var + 1e-5f));
}

// router with fused rmsnorm; top-2 softmax -> combine weights [tok][4]
__global__ __launch_bounds__(256) void gate_k(const float* __restrict__ x2,
                                              const float* __restrict__ nw,
                                              const float* __restrict__ gw,
                                              const float* __restrict__ gb,
                                              float* __restrict__ w4) {
  const int tid = threadIdx.x;
  const int wave = tid >> 6, lane = tid & 63;
  const long t = (long)blockIdx.x * 4 + wave;
  float a0 = 0, a1 = 0, a2 = 0, a3 = 0, ssq = 0;
#pragma unroll
  for (int i = 0; i < 16; ++i) {
    int d = lane + i * 64;
    float xv = x2[t * 1024 + d];
    ssq += xv * xv;
    float h = xv * nw[d];
    float4 w = ((const float4*)gw)[d];
    a0 += h * w.x; a1 += h * w.y; a2 += h * w.z; a3 += h * w.w;
  }
#pragma unroll
  for (int off = 32; off > 0; off >>= 1) {
    a0 += __shfl_xor(a0, off); a1 += __shfl_xor(a1, off);
    a2 += __shfl_xor(a2, off); a3 += __shfl_xor(a3, off);
    ssq += __shfl_xor(ssq, off);
  }
  if (lane == 0) {
    float nr = rsqrtf(ssq * (1.f / 1024.f) + 1e-6f);
    float lg[4] = {a0 * nr + gb[0], a1 * nr + gb[1], a2 * nr + gb[2], a3 * nr + gb[3]};
    int i0 = 0;
    for (int e = 1; e < 4; ++e)
      if (lg[e] > lg[i0]) i0 = e;
    int i1 = -1;
    for (int e = 0; e < 4; ++e) {
      if (e == i0) continue;
      if (i1 < 0 || lg[e] > lg[i1]) i1 = e;
    }
    float e1 = __expf(lg[i1] - lg[i0]);
    float p0 = 1.f / (1.f + e1), p1 = e1 / (1.f + e1);
    float o[4] = {0.f, 0.f, 0.f, 0.f};
    o[i0] = p0; o[i1] = p1;
    w4[t * 4 + 0] = o[0]; w4[t * 4 + 1] = o[1];
    w4[t * 4 + 2] = o[2]; w4[t * 4 + 3] = o[3];
  }
}

// Build 128-padded concat token list across experts + tile->expert table.
__global__ __launch_bounds__(256) void build2_k(const float* __restrict__ w4,
                                                int* __restrict__ cidx,
                                                int* __restrict__ meta) {
  __shared__ int ps[256];
  __shared__ int tbase_s;
  const int tid = threadIdx.x;
  if (tid == 0) tbase_s = 0;
  __syncthreads();
  for (int e = 0; e < 4; ++e) {
    const int base = tid * 16;
    unsigned char loc[16];
    int c = 0;
#pragma unroll
    for (int i = 0; i < 16; ++i)
      if (w4[(long)(base + i) * 4 + e] != 0.f) loc[c++] = (unsigned char)i;
    ps[tid] = c;
    __syncthreads();
    for (int off = 1; off < 256; off <<= 1) {
      int v = (tid >= off) ? ps[tid - off] : 0;
      __syncthreads();
      ps[tid] += v;
      __syncthreads();
    }
    const int total = ps[255];
    const int p = ps[tid] - c;
    const int tbase = tbase_s;
    const int rowbase = tbase * 128;
    for (int i = 0; i < c; ++i) cidx[rowbase + p + i] = base + (int)loc[i];
    const int tiles = (total + 127) >> 7;
    for (int j = total + tid; j < tiles * 128; j += 256) cidx[rowbase + j] = -1;
    for (int j = tid; j < tiles; j += 256) meta[1 + tbase + j] = e;
    __syncthreads();
    if (tid == 0) tbase_s = tbase + tiles;
    __syncthreads();
  }
  if (tid == 0) meta[0] = tbase_s;
}

// gather h2b rows into packed A for the merged W1 GEMM (16B per thread)
__global__ __launch_bounds__(256) void packA_k(const bf16_t* __restrict__ h2b,
                                               const int* __restrict__ cidx,
                                               bf16_t* __restrict__ apack) {
  long idx = (long)blockIdx.x * 256 + threadIdx.x;  // 8704*128 chunks
  long row = idx >> 7;
  int ch = (int)(idx & 127);
  int t = cidx[row];
  float4 v = make_float4(0.f, 0.f, 0.f, 0.f);
  if (t >= 0) v = ((const float4*)(h2b + (long)t * 1024))[ch];
  ((float4*)(apack + row * 1024))[ch] = v;
}

extern "C" void kernel_launch(void* const* d_in, const int* in_sizes, int n_in,
                              void* d_out, int out_size, void* d_ws, size_t ws_size,
                              hipStream_t stream) {
  const float* x = (const float*)d_in[0];
  const float* n1w = (const float*)d_in[1];
  const float* n2w = (const float*)d_in[2];
  const float* inpw = (const float*)d_in[3];
  const float* inpb = (const float*)d_in[4];
  const float* convw = (const float*)d_in[5];
  const float* convb = (const float*)d_in[6];
  const float* dtw = (const float*)d_in[7];
  const float* dtb = (const float*)d_in[8];
  const float* bpw = (const float*)d_in[9];
  const float* bpb = (const float*)d_in[10];
  const float* cpw = (const float*)d_in[11];
  const float* cpb = (const float*)d_in[12];
  const float* s2iw = (const float*)d_in[13];
  const float* s2ib = (const float*)d_in[14];
  const float* Dp = (const float*)d_in[15];
  const float* outw = (const float*)d_in[16];
  const float* outb_ = (const float*)d_in[17];
  const float* gatew = (const float*)d_in[18];
  const float* gateb = (const float*)d_in[19];
  const float* ew1 = (const float*)d_in[20];
  const float* eb1 = (const float*)d_in[21];
  const float* ew2 = (const float*)d_in[22];
  const float* eb2 = (const float*)d_in[23];
  float* out = (float*)d_out;

  char* ws = (char*)d_ws;
  size_t off = 0;
  auto alloc = [&](size_t bytes) -> void* {
    void* p = (void*)(ws + off);
    off += (bytes + 255) & ~(size_t)255;
    return p;
  };

  float* biasdt = (float*)alloc(256 * 4);
  float* ybuf = (float*)alloc((size_t)NTOK * 64 * 4);      // \ contiguous; later
  bf16_t* ylnb = (bf16_t*)alloc((size_t)NTOK * 64 * 2);    //  reused as apack
  float* x2 = (float*)alloc((size_t)NTOK * 1024 * 4);      // /  (18.3 >= 17.8 MB)
  bf16_t* h2b = (bf16_t*)alloc((size_t)NTOK * 1024 * 2);
  float* w4 = (float*)alloc((size_t)NTOK * 4 * 4);
  int* cidx = (int*)alloc((size_t)68 * 128 * 4);
  int* meta = (int*)alloc(128 * 4);
  bf16_t* apack = (bf16_t*)ybuf;  // aliases ybuf+ylnb+x2 (dead by packA time)

  // Aliased region. Mixer phase:   [0,32M) xzb | [32M,48M) xsb | [48M,52M) dtbc
  //                                 [52M,68M) zb
  // Weights (die before clobber):  [64M,72M) inpT | [72M,76M) outT | [76M,84M) h1b
  //                                 [84M,85M) wdtT | [85M,85.25M) s2iT
  // MoE phase (after mixer):       [0,32M) w1T | [32M,64M) w2T | [64M,132M) hidb
  const size_t REG_SZ = 64 * (size_t)MB + (size_t)8704 * 4096 * 2;
  char* reg = (char*)alloc(REG_SZ);
  bf16_t* xzb = (bf16_t*)reg;
  bf16_t* xsb = (bf16_t*)(reg + 32 * (size_t)MB);
  float* dtbc = (float*)(reg + 48 * (size_t)MB);
  bf16_t* zb = (bf16_t*)(reg + 52 * (size_t)MB);
  bf16_t* inpT = (bf16_t*)(reg + 64 * (size_t)MB);
  bf16_t* outT = (bf16_t*)(reg + 72 * (size_t)MB);
  bf16_t* h1b = (bf16_t*)(reg + 76 * (size_t)MB);
  bf16_t* wdtT = (bf16_t*)(reg + 84 * (size_t)MB);
  bf16_t* s2iT = (bf16_t*)(reg + 85 * (size_t)MB);
  bf16_t* w1T = (bf16_t*)reg;
  bf16_t* w2T = (bf16_t*)(reg + 32 * (size_t)MB);
  bf16_t* hidb = (bf16_t*)(reg + 64 * (size_t)MB);

  dim3 tb(32, 8);
  dtbias_k<<<1, 256, 0, stream>>>(dtb, bpb, cpb, biasdt);
  tcast_k<<<dim3(128, 32), tb, 0, stream>>>(inpw, inpT, 1024, 4096, 0, 0);
  tcast_k<<<dim3(2, 64), tb, 0, stream>>>(dtw, wdtT, 2048, 64, 0, 0);
  tcast_k<<<dim3(2, 64), tb, 0, stream>>>(bpw, wdtT + (size_t)64 * 2048, 2048, 64, 0, 0);
  tcast_k<<<dim3(2, 64), tb, 0, stream>>>(cpw, wdtT + (size_t)128 * 2048, 2048, 64, 0, 0);
  // wdtT rows 192-255: 0xAA poison bf16 = -1.2e-13; harmless (cols never read)
  tcast_k<<<dim3(64, 2), tb, 0, stream>>>(s2iw, s2iT, 64, 2048, 0, 0);
  tcast_k<<<dim3(32, 64), tb, 0, stream>>>(outw, outT, 2048, 1024, 0, 0);

  // ---- mixer ----
  rmsnorm_k<<<NTOK, 256, 0, stream>>>(x, n1w, h1b);
  gemm_bt<5, 128><<<dim3(32, 32), 256, 0, stream>>>(h1b, inpT, NTOK, 4096, 1024,
      nullptr, xzb, inpb, nullptr, 0, nullptr, 0, nullptr, 0, nullptr, nullptr,
      nullptr, nullptr, nullptr);
  conv_silu_k<<<(NTOK * 2048) / 256, 256, 0, stream>>>(xzb, convw, convb, xsb);
  gemm_bt<0, 64><<<dim3(4, 32), 256, 0, stream>>>(xsb, wdtT, NTOK, 256, 2048,
      dtbc, nullptr, biasdt, nullptr, 0, nullptr, 0, nullptr, 0, nullptr, nullptr,
      nullptr, nullptr, nullptr);
  scan_k<<<128, 256, 0, stream>>>(dtbc, ybuf);
  ln64_k<<<NTOK / 4, 256, 0, stream>>>(ybuf, ylnb);
  gemm_bt<1, 128><<<dim3(16, 32), 256, 0, stream>>>(ylnb, s2iT, NTOK, 2048, 64,
      nullptr, zb, s2ib, xsb, 2048, xzb + 2048, 4096, nullptr, 0, Dp, nullptr,
      nullptr, nullptr, nullptr);
  gemm_bt<2, 64><<<dim3(16, 32), 256, 0, stream>>>(zb, outT, NTOK, 1024, 2048,
      x2, nullptr, outb_, nullptr, 0, nullptr, 0, x, 1024, nullptr, nullptr, out,
      nullptr, nullptr);

  // ---- MoE (top-2 sparse, merged across experts) ----
  tcast_k<<<dim3(128, 32, 4), tb, 0, stream>>>(ew1, w1T, 1024, 4096,
      (long)1024 * 4096, (long)4096 * 1024);
  tcast_k<<<dim3(32, 128, 4), tb, 0, stream>>>(ew2, w2T, 4096, 1024,
      (long)4096 * 1024, (long)1024 * 4096);
  rmsnorm_k<<<NTOK, 256, 0, stream>>>(x2, n2w, h2b);
  gate_k<<<NTOK / 4, 256, 0, stream>>>(x2, n2w, gatew, gateb, w4);
  build2_k<<<1, 256, 0, stream>>>(w4, cidx, meta);
  packA_k<<<(8704 * 128) / 256, 256, 0, stream>>>(h2b, cidx, apack);
  // all-expert W1 + gelu -> hidb (concat rows)
  gemm_bt<7, 128><<<dim3(32, 68), 256, 0, stream>>>(apack, w1T, 8704, 4096, 1024,
      nullptr, hidb, eb1, nullptr, 0, nullptr, 0, nullptr, 0, nullptr, nullptr,
      nullptr, cidx, meta);
  // all-expert W2, scatter-accumulate into out
  gemm_bt<8, 64><<<dim3(16, 68), 256, 0, stream>>>(hidb, w2T, 8704, 1024, 4096,
      out, nullptr, eb2, nullptr, 0, nullptr, 0, nullptr, 0, nullptr, w4,
      nullptr, cidx, meta);
}